// Round 8
// baseline (105.742 us; speedup 1.0000x reference)
//
#include <hip/hip_runtime.h>

typedef unsigned long long u64;
typedef unsigned int u32;

// ---------------- packed weights / integer thresholds (device globals) ------
__device__ u32 g_w1b[32];                 // 9 taps in low bits
__device__ u32 g_w2b[64 * 3];             // [c][k], bit = cin (0..31)
__device__ u64 g_w3b[128 * 3];            // [c][k], bit = cin (0..63)
__device__ u64 g_w4b[128 * 6 * 2];        // [c][h][hi], bit l = cin hi*64+l
__device__ u64 g_wfcb[6 * 32];            // [j][k]: w=k%16, hi=k/16, bit l -> i=(hi*64+l)*16+w
__device__ float g_bfc[6];

__device__ int g_s1[32], g_s2[64], g_s3[128], g_s4[128];   // integer S-thresholds
__device__ u64 g_flip1, g_flip2, g_flip3[2], g_flip4[2];   // per-layer flip masks

struct Ptrs { const float* p[27]; };

// exact f32 op order of the np reference: y = ((S + b) * inv) + t, no FMA
__device__ __forceinline__ int predS(int S, float b, float inv, float t) {
  float hv = __fadd_rn((float)S, b);
  float y = __fadd_rn(__fmul_rn(hv, inv), t);
  return y > 0.0f;
}

__device__ __forceinline__ void bn_fold(float b, float g, float be, float m, float v,
                                        float* ob, float* oinv, float* ot) {
  double iv = (double)g * (1.0 / sqrt((double)v + 1e-5));
  float invf = (float)iv;
  *ob = b;
  *oinv = invf;
  *ot = __fadd_rn(be, -__fmul_rn(m, invf));
}

// pred(S) == (S >= smin) XOR flip, exactly, for all integer S in range.
__device__ __forceinline__ void find_thr(float bias, float g, float be, float m, float v,
                                         int* smin, int* flip) {
  float b, inv, t;
  bn_fold(bias, g, be, m, v, &b, &inv, &t);
  int pl = predS(-2048, b, inv, t), ph = predS(2048, b, inv, t);
  if (pl && ph) { *smin = -4096; *flip = 0; }
  else if (!pl && !ph) { *smin = 4096; *flip = 0; }
  else if (!pl && ph) {
    int lo = -2048, hi = 2048;
    while (hi - lo > 1) { int md = (lo + hi) >> 1; if (predS(md, b, inv, t)) hi = md; else lo = md; }
    *smin = hi; *flip = 0;
  } else {
    int lo = -2048, hi = 2048;
    while (hi - lo > 1) { int md = (lo + hi) >> 1; if (predS(md, b, inv, t)) lo = md; else hi = md; }
    *smin = lo + 1; *flip = 1;
  }
}

// -------------------------- weight prepack ---------------------------------
__global__ __launch_bounds__(256) void prepack_kernel(Ptrs P) {
  int tid = threadIdx.x;
  int gid = blockIdx.x * 256 + tid;
  if (gid < 32) {
    int c = gid, smin, flip;
    find_thr(P.p[2][c], P.p[3][c], P.p[4][c], P.p[5][c], P.p[6][c], &smin, &flip);
    g_s1[c] = smin;
    u64 fl = __ballot(flip != 0);
    if (c == 0) g_flip1 = (fl & 0xFFFFFFFFULL) | (fl << 32);
  } else if (gid >= 64 && gid < 128) {
    int c = gid - 64, smin, flip;
    find_thr(P.p[8][c], P.p[9][c], P.p[10][c], P.p[11][c], P.p[12][c], &smin, &flip);
    g_s2[c] = smin;
    u64 fl = __ballot(flip != 0);
    if (c == 0) g_flip2 = fl;
  } else if (gid >= 128 && gid < 256) {
    int c = gid - 128, smin, flip;
    find_thr(P.p[14][c], P.p[15][c], P.p[16][c], P.p[17][c], P.p[18][c], &smin, &flip);
    g_s3[c] = smin;
    u64 fl = __ballot(flip != 0);
    if ((c & 63) == 0) g_flip3[c >> 6] = fl;
  } else if (gid >= 256 && gid < 384) {
    int c = gid - 256, smin, flip;
    find_thr(P.p[20][c], P.p[21][c], P.p[22][c], P.p[23][c], P.p[24][c], &smin, &flip);
    g_s4[c] = smin;
    u64 fl = __ballot(flip != 0);
    if ((c & 63) == 0) g_flip4[c >> 6] = fl;
  } else if (gid >= 384 && gid < 416) {
    int c = gid - 384;
    u32 b = 0;
    for (int k = 0; k < 9; ++k)
      if (P.p[1][c * 9 + k] > 0.0f) b |= (1u << k);
    g_w1b[c] = b;
  } else if (gid >= 416 && gid < 422) {
    g_bfc[gid - 416] = P.p[26][gid - 416];
  } else if (gid >= 512 && gid < 704) {
    int idx = gid - 512;
    int c = idx / 3, k = idx % 3;
    u32 b = 0;
    for (int cin = 0; cin < 32; ++cin)
      if (P.p[7][(c * 32 + cin) * 3 + k] > 0.0f) b |= (1u << cin);
    g_w2b[c * 3 + k] = b;
  } else if (gid >= 704 && gid < 1088) {
    int idx = gid - 704;
    int c = idx / 3, k = idx % 3;
    u64 b = 0;
    for (int cin = 0; cin < 64; ++cin)
      if (P.p[13][(c * 64 + cin) * 3 + k] > 0.0f) b |= (1ull << cin);
    g_w3b[c * 3 + k] = b;
  } else if (gid >= 1088 && gid < 2624) {
    int idx = gid - 1088;
    int c = idx / 12, r = idx % 12, h = r >> 1, hi = r & 1;
    u64 b = 0;
    for (int l = 0; l < 64; ++l) {
      int cin = hi * 64 + l;
      if (P.p[19][(c * 128 + cin) * 6 + h] > 0.0f) b |= (1ull << l);
    }
    g_w4b[(c * 6 + h) * 2 + hi] = b;
  } else if (gid >= 2624 && gid < 2816) {
    int idx = gid - 2624;
    int j = idx / 32, k = idx % 32;
    int w = k & 15, hi = k >> 4;
    u64 b = 0;
    for (int l = 0; l < 64; ++l) {
      int i = (hi * 64 + l) * 16 + w;
      if (P.p[25][j * 2048 + i] > 0.0f) b |= (1ull << l);
    }
    g_wfcb[j * 32 + k] = b;
  }
}

// ----------------------- fused binary network ------------------------------
// THREE WAVES PER IMAGE (2 rows each; conv1..conv3 are row-local and live in
// wave-uniform SGPRs). 2 images per 384-thread block. Conv4 (k=6,1) on waves
// 0/1 (one channel-half each) after a barrier; FC on wave 0.
struct WaveMem {
  alignas(16) u64 p3s[192];   // conv3+pool out (h*16+pw)*2+chanhalf
  u64 c4s[32];                // conv4 out w*2+chanhalf
};

__global__ __launch_bounds__(384) void fused_kernel(const float* __restrict__ x,
                                                    float* __restrict__ out, int B) {
  const int tid = threadIdx.x;
  const int lane = tid & 63;
  const int wave = tid >> 6;         // 0..5
  const int img = (wave >= 3);       // 0..1 within block
  const int rsub = wave - img * 3;   // 0..2 : row-pair of the image
  const int n = blockIdx.x * 2 + img;
  const bool active = (n < B);

  __shared__ WaveMem wm[2];
  WaveMem& W = wm[img];
  const float* xi = x + (size_t)n * 768;

  if (active) {
    // ---- per-lane constants for conv1..conv3 ----
    const int c1 = lane & 31;
    const bool isSub1 = (lane >= 32);
    const u32 wv = g_w1b[c1];
    const u32 wv2 = wv << 2;
    const int s1v = g_s1[c1];
    const int D0i = (9 - s1v) >> 1;
    const int D0a = (5 - s1v + 2 * __popc(wv & 0x00F)) >> 1;
    const int D0b = (8 - s1v + 2 * __popc(wv & 0x100)) >> 1;
    const int D1a = (7 - s1v + 2 * __popc(wv & 0x003)) >> 1;
    const int D1b = (6 - s1v + 2 * __popc(wv & 0x1C0)) >> 1;
    const u64 fl1 = g_flip1;

    const u32 w0m = g_w2b[lane * 3 + 0];
    const u32 w1m = g_w2b[lane * 3 + 1];
    const u32 w2m = g_w2b[lane * 3 + 2];
    const int s2v = g_s2[lane];
    const int D96h = (96 - s2v) >> 1, D64h = (64 - s2v) >> 1;
    const u64 fl2 = g_flip2;

    const u32* w3p = (const u32*)g_w3b;
    const u32 wl0l = w3p[(lane * 3 + 0) * 2], wl0h = w3p[(lane * 3 + 0) * 2 + 1];
    const u32 wl1l = w3p[(lane * 3 + 1) * 2], wl1h = w3p[(lane * 3 + 1) * 2 + 1];
    const u32 wl2l = w3p[(lane * 3 + 2) * 2], wl2h = w3p[(lane * 3 + 2) * 2 + 1];
    const u32 wh0l = w3p[((64 + lane) * 3 + 0) * 2], wh0h = w3p[((64 + lane) * 3 + 0) * 2 + 1];
    const u32 wh1l = w3p[((64 + lane) * 3 + 1) * 2], wh1h = w3p[((64 + lane) * 3 + 1) * 2 + 1];
    const u32 wh2l = w3p[((64 + lane) * 3 + 2) * 2], wh2h = w3p[((64 + lane) * 3 + 2) * 2 + 1];
    const int sa = g_s3[lane], sb = g_s3[64 + lane];
    const int Da192h = (192 - sa) >> 1, Da128h = (128 - sa) >> 1;
    const int Db192h = (192 - sb) >> 1, Db128h = (128 - sb) >> 1;
    const u64 f3a = g_flip3[0], f3b = g_flip3[1];

    // ---- process this wave's 2 rows ----
    #pragma unroll
    for (int hl = 0; hl < 2; ++hl) {
      const int h = rsub * 2 + hl;
      // stage A: binarize row into padded (<<4) form; all wave-uniform
      float v0 = xi[h * 128 + lane];
      float v1 = xi[h * 128 + 64 + lane];
      u64 m0 = __ballot(v0 > 0.0f);
      u64 m1 = __ballot(v1 > 0.0f);
      const u64 ra = m0 << 4;
      const u64 rb = (m0 >> 60) | (m1 << 4);
      const u64 rc = m1 >> 60;

      // conv1 + sign + pool: 16 ballots -> a64[j] covers pooled pos 2j,2j+1
      u64 a64[16];
      #pragma unroll
      for (int j = 0; j < 16; ++j) {
        u64 lo = (j < 8) ? ra : rb;
        u64 hi = (j < 8) ? rb : rc;
        const int sh = (8 * j) & 63;
        u64 Wq = (lo >> sh) | ((hi << 1) << (63 - sh));   // 15-bit superwindow
        u32 W0 = (u32)Wq & 0x7FF;
        u32 W1 = ((u32)Wq >> 4) & 0x7FF;
        u32 Wv = isSub1 ? W1 : W0;       // sub0 half: pooled 2j; sub1: 2j+1
        int P0 = __popc((Wv ^ wv) & 0x1FF);
        int P1 = __popc((Wv ^ wv2) & 0x7FC);
        int D0 = D0i, D1 = D0i;
        if (j == 0)  { D0 = isSub1 ? D0i : D0a; D1 = isSub1 ? D0i : D1a; }
        if (j == 15) { D0 = isSub1 ? D0b : D0i; D1 = isSub1 ? D1b : D0i; }
        a64[j] = (__ballot(P0 <= D0) ^ fl1) | (__ballot(P1 <= D1) ^ fl1);
      }

      // u32 view of pooled row (static index -> SALU extract)
      auto AW = [&](int w) -> u32 {
        u64 v = a64[w >> 1];
        return (w & 1) ? (u32)(v >> 32) : (u32)v;
      };
      // conv2 (32->64, k=3, pad1) + sign: one ballot per position
      auto CONV2 = [&](int w, u32 am, u32 ac, u32 ap) -> u64 {
        int P, D;
        if (w == 0)       { P = __popc(ac ^ w1m) + __popc(ap ^ w2m); D = D64h; }
        else if (w == 31) { P = __popc(am ^ w0m) + __popc(ac ^ w1m); D = D64h; }
        else { P = __popc(am ^ w0m) + __popc(ac ^ w1m) + __popc(ap ^ w2m); D = D96h; }
        return __ballot(P <= D) ^ fl2;
      };
      // conv3 (64->128, k=3, pad1) + sign + pool; kind: 0=pw0, 1=mid, 2=pw15
      auto CONV3 = [&](int kind, u64 Au, u64 Bu, u64 Cu, u64 Du, int pt) {
        u32 Al = (u32)Au, Ah = (u32)(Au >> 32);
        u32 Bl = (u32)Bu, Bh = (u32)(Bu >> 32);
        u32 Cl = (u32)Cu, Ch = (u32)(Cu >> 32);
        u32 Dl = (u32)Du, Dh = (u32)(Du >> 32);
        int P0a, P1a, P0b, P1b, E0a, E1a, E0b, E1b;
        if (kind == 0) {       // out0 short (B,C taps1,2), out1 full (B,C,D)
          P0a = __popc(Bl^wl1l)+__popc(Bh^wl1h)+__popc(Cl^wl2l)+__popc(Ch^wl2h);
          P1a = __popc(Bl^wl0l)+__popc(Bh^wl0h)+__popc(Cl^wl1l)+__popc(Ch^wl1h)
              + __popc(Dl^wl2l)+__popc(Dh^wl2h);
          P0b = __popc(Bl^wh1l)+__popc(Bh^wh1h)+__popc(Cl^wh2l)+__popc(Ch^wh2h);
          P1b = __popc(Bl^wh0l)+__popc(Bh^wh0h)+__popc(Cl^wh1l)+__popc(Ch^wh1h)
              + __popc(Dl^wh2l)+__popc(Dh^wh2h);
          E0a = Da128h; E1a = Da192h; E0b = Db128h; E1b = Db192h;
        } else if (kind == 2) { // out0 full (A,B,C), out1 short (B,C taps0,1)
          P0a = __popc(Al^wl0l)+__popc(Ah^wl0h)+__popc(Bl^wl1l)+__popc(Bh^wl1h)
              + __popc(Cl^wl2l)+__popc(Ch^wl2h);
          P1a = __popc(Bl^wl0l)+__popc(Bh^wl0h)+__popc(Cl^wl1l)+__popc(Ch^wl1h);
          P0b = __popc(Al^wh0l)+__popc(Ah^wh0h)+__popc(Bl^wh1l)+__popc(Bh^wh1h)
              + __popc(Cl^wh2l)+__popc(Ch^wh2h);
          P1b = __popc(Bl^wh0l)+__popc(Bh^wh0h)+__popc(Cl^wh1l)+__popc(Ch^wh1h);
          E0a = Da192h; E1a = Da128h; E0b = Db192h; E1b = Db128h;
        } else {
          P0a = __popc(Al^wl0l)+__popc(Ah^wl0h)+__popc(Bl^wl1l)+__popc(Bh^wl1h)
              + __popc(Cl^wl2l)+__popc(Ch^wl2h);
          P1a = __popc(Bl^wl0l)+__popc(Bh^wl0h)+__popc(Cl^wl1l)+__popc(Ch^wl1h)
              + __popc(Dl^wl2l)+__popc(Dh^wl2h);
          P0b = __popc(Al^wh0l)+__popc(Ah^wh0h)+__popc(Bl^wh1l)+__popc(Bh^wh1h)
              + __popc(Cl^wh2l)+__popc(Ch^wh2h);
          P1b = __popc(Bl^wh0l)+__popc(Bh^wh0h)+__popc(Cl^wh1l)+__popc(Ch^wh1h)
              + __popc(Dl^wh2l)+__popc(Dh^wh2h);
          E0a = Da192h; E1a = Da192h; E0b = Db192h; E1b = Db192h;
        }
        u64 mm0 = (__ballot(P0a <= E0a) ^ f3a) | (__ballot(P1a <= E1a) ^ f3a);
        u64 mm1 = (__ballot(P0b <= E0b) ^ f3b) | (__ballot(P1b <= E1b) ^ f3b);
        if (lane == 0) { W.p3s[2 * pt] = mm0; W.p3s[2 * pt + 1] = mm1; }
      };

      const int pt0 = h * 16;
      // software-pipelined conv2 -> conv3 over the row
      u64 cw0 = CONV2(0, AW(0), AW(0), AW(1));
      u64 cw1 = CONV2(1, AW(0), AW(1), AW(2));
      u64 cw2 = CONV2(2, AW(1), AW(2), AW(3));
      CONV3(0, cw0, cw0, cw1, cw2, pt0);           // pw=0: B=c2[0],C=c2[1],D=c2[2]
      u64 Ar = cw1, Br = cw2;                      // c2[2pw-1], c2[2pw] for pw=1
      #pragma unroll
      for (int pw = 1; pw <= 14; ++pw) {
        u64 Cr = CONV2(2 * pw + 1, AW(2 * pw), AW(2 * pw + 1), AW(2 * pw + 2));
        u64 Dr = CONV2(2 * pw + 2, AW(2 * pw + 1), AW(2 * pw + 2), AW(2 * pw + 3));
        CONV3(1, Ar, Br, Cr, Dr, pt0 + pw);
        Ar = Cr; Br = Dr;
      }
      u64 C15 = CONV2(31, AW(30), AW(31), AW(31));
      CONV3(2, Ar, Br, C15, C15, pt0 + 15);        // pw=15: A=c2[29],B=c2[30],C=c2[31]
    }
  }

  __syncthreads();   // conv4 mixes rows across the three waves

  if (active && rsub < 2) {
    // ---- conv4 (128->128, k=(6,1)) + sign — one channel-half per wave ----
    const int half = rsub;
    const u32* w4 = (const u32*)g_w4b;
    const int c = half * 64 + lane;
    u32 wt[24];
    #pragma unroll
    for (int h = 0; h < 6; ++h) {
      wt[h * 4 + 0] = w4[(c * 6 + h) * 4 + 0];
      wt[h * 4 + 1] = w4[(c * 6 + h) * 4 + 1];
      wt[h * 4 + 2] = w4[(c * 6 + h) * 4 + 2];
      wt[h * 4 + 3] = w4[(c * 6 + h) * 4 + 3];
    }
    const int Dch = (768 - g_s4[c]) >> 1;
    const u64 fl4 = half ? g_flip4[1] : g_flip4[0];
    #pragma unroll 2
    for (int w = 0; w < 16; ++w) {
      int acc = 0;
      #pragma unroll
      for (int h = 0; h < 6; ++h) {
        const u32* p = (const u32*)&W.p3s[(h * 16 + w) * 2];
        acc += __popc(p[0] ^ wt[h * 4 + 0]) + __popc(p[1] ^ wt[h * 4 + 1])
             + __popc(p[2] ^ wt[h * 4 + 2]) + __popc(p[3] ^ wt[h * 4 + 3]);
      }
      u64 m = __ballot(acc <= Dch) ^ fl4;
      if (lane == 0) W.c4s[2 * w + half] = m;
    }
  }

  __syncthreads();   // FC reads both channel halves

  if (active && rsub == 0) {
    // ---- FC: sign(h) . sign(wfc)^T + bfc  (shuffle reduce) ----
    const int k = lane & 31, hf = lane >> 5;
    u64 hw = W.c4s[(k & 15) * 2 + (k >> 4)];
    #pragma unroll
    for (int it = 0; it < 3; ++it) {
      int j = 2 * it + hf;
      int pc = __popcll(hw ^ g_wfcb[j * 32 + k]);
      pc += __shfl_xor(pc, 16);
      pc += __shfl_xor(pc, 8);
      pc += __shfl_xor(pc, 4);
      pc += __shfl_xor(pc, 2);
      pc += __shfl_xor(pc, 1);
      if (k == 0)
        out[(size_t)n * 6 + j] = __fadd_rn((float)(2048 - 2 * pc), g_bfc[j]);
    }
  }
}

// ------------------------------ launch --------------------------------------
extern "C" void kernel_launch(void* const* d_in, const int* in_sizes, int n_in,
                              void* d_out, int out_size, void* d_ws, size_t ws_size,
                              hipStream_t stream) {
  (void)d_ws; (void)ws_size; (void)n_in;
  Ptrs P;
  for (int i = 0; i < 27; ++i) P.p[i] = (const float*)d_in[i];

  hipLaunchKernelGGL(prepack_kernel, dim3(11), dim3(256), 0, stream, P);

  const float* x = (const float*)d_in[0];
  float* out = (float*)d_out;
  int B = in_sizes[0] / 768;                 // 4096
  hipLaunchKernelGGL(fused_kernel, dim3((B + 1) / 2), dim3(384), 0, stream, x, out, B);
}

// Round 9
// 84.584 us; speedup vs baseline: 1.2501x; 1.2501x over previous
//
#include <hip/hip_runtime.h>

typedef unsigned long long u64;
typedef unsigned int u32;

// ---------------- packed weights / integer thresholds (device globals) ------
__device__ u32 g_w1b[32];                 // 9 taps in low bits
__device__ u32 g_w2b[64 * 3];             // [c][k], bit = cin (0..31)
__device__ u64 g_w3b[128 * 3];            // [c][k], bit = cin (0..63)
__device__ u64 g_w4b[128 * 6 * 2];        // [c][h][hi], bit l = cin hi*64+l
__device__ u64 g_wfcb[6 * 32];            // [j][k]: w=k%16, hi=k/16, bit l -> i=(hi*64+l)*16+w
__device__ float g_bfc[6];

__device__ int g_s1[32], g_s2[64], g_s3[128], g_s4[128];   // integer S-thresholds
__device__ u64 g_flip1, g_flip2, g_flip3[2], g_flip4[2];   // per-layer flip masks

struct Ptrs { const float* p[27]; };

// exact f32 op order of the np reference: y = ((S + b) * inv) + t, no FMA
__device__ __forceinline__ int predS(int S, float b, float inv, float t) {
  float hv = __fadd_rn((float)S, b);
  float y = __fadd_rn(__fmul_rn(hv, inv), t);
  return y > 0.0f;
}

__device__ __forceinline__ void bn_fold(float b, float g, float be, float m, float v,
                                        float* ob, float* oinv, float* ot) {
  double iv = (double)g * (1.0 / sqrt((double)v + 1e-5));
  float invf = (float)iv;
  *ob = b;
  *oinv = invf;
  *ot = __fadd_rn(be, -__fmul_rn(m, invf));
}

// pred(S) == (S >= smin) XOR flip, exactly, for all integer S in range.
__device__ __forceinline__ void find_thr(float bias, float g, float be, float m, float v,
                                         int* smin, int* flip) {
  float b, inv, t;
  bn_fold(bias, g, be, m, v, &b, &inv, &t);
  int pl = predS(-2048, b, inv, t), ph = predS(2048, b, inv, t);
  if (pl && ph) { *smin = -4096; *flip = 0; }
  else if (!pl && !ph) { *smin = 4096; *flip = 0; }
  else if (!pl && ph) {
    int lo = -2048, hi = 2048;
    while (hi - lo > 1) { int md = (lo + hi) >> 1; if (predS(md, b, inv, t)) hi = md; else lo = md; }
    *smin = hi; *flip = 0;
  } else {
    int lo = -2048, hi = 2048;
    while (hi - lo > 1) { int md = (lo + hi) >> 1; if (predS(md, b, inv, t)) lo = md; else hi = md; }
    *smin = lo + 1; *flip = 1;
  }
}

// -------------------------- weight prepack ---------------------------------
__global__ __launch_bounds__(256) void prepack_kernel(Ptrs P) {
  int tid = threadIdx.x;
  int gid = blockIdx.x * 256 + tid;
  if (gid < 32) {
    int c = gid, smin, flip;
    find_thr(P.p[2][c], P.p[3][c], P.p[4][c], P.p[5][c], P.p[6][c], &smin, &flip);
    g_s1[c] = smin;
    u64 fl = __ballot(flip != 0);
    if (c == 0) g_flip1 = (fl & 0xFFFFFFFFULL) | (fl << 32);
  } else if (gid >= 64 && gid < 128) {
    int c = gid - 64, smin, flip;
    find_thr(P.p[8][c], P.p[9][c], P.p[10][c], P.p[11][c], P.p[12][c], &smin, &flip);
    g_s2[c] = smin;
    u64 fl = __ballot(flip != 0);
    if (c == 0) g_flip2 = fl;
  } else if (gid >= 128 && gid < 256) {
    int c = gid - 128, smin, flip;
    find_thr(P.p[14][c], P.p[15][c], P.p[16][c], P.p[17][c], P.p[18][c], &smin, &flip);
    g_s3[c] = smin;
    u64 fl = __ballot(flip != 0);
    if ((c & 63) == 0) g_flip3[c >> 6] = fl;
  } else if (gid >= 256 && gid < 384) {
    int c = gid - 256, smin, flip;
    find_thr(P.p[20][c], P.p[21][c], P.p[22][c], P.p[23][c], P.p[24][c], &smin, &flip);
    g_s4[c] = smin;
    u64 fl = __ballot(flip != 0);
    if ((c & 63) == 0) g_flip4[c >> 6] = fl;
  } else if (gid >= 384 && gid < 416) {
    int c = gid - 384;
    u32 b = 0;
    for (int k = 0; k < 9; ++k)
      if (P.p[1][c * 9 + k] > 0.0f) b |= (1u << k);
    g_w1b[c] = b;
  } else if (gid >= 416 && gid < 422) {
    g_bfc[gid - 416] = P.p[26][gid - 416];
  } else if (gid >= 512 && gid < 704) {
    int idx = gid - 512;
    int c = idx / 3, k = idx % 3;
    u32 b = 0;
    for (int cin = 0; cin < 32; ++cin)
      if (P.p[7][(c * 32 + cin) * 3 + k] > 0.0f) b |= (1u << cin);
    g_w2b[c * 3 + k] = b;
  } else if (gid >= 704 && gid < 1088) {
    int idx = gid - 704;
    int c = idx / 3, k = idx % 3;
    u64 b = 0;
    for (int cin = 0; cin < 64; ++cin)
      if (P.p[13][(c * 64 + cin) * 3 + k] > 0.0f) b |= (1ull << cin);
    g_w3b[c * 3 + k] = b;
  } else if (gid >= 1088 && gid < 2624) {
    int idx = gid - 1088;
    int c = idx / 12, r = idx % 12, h = r >> 1, hi = r & 1;
    u64 b = 0;
    for (int l = 0; l < 64; ++l) {
      int cin = hi * 64 + l;
      if (P.p[19][(c * 128 + cin) * 6 + h] > 0.0f) b |= (1ull << l);
    }
    g_w4b[(c * 6 + h) * 2 + hi] = b;
  } else if (gid >= 2624 && gid < 2816) {
    int idx = gid - 2624;
    int j = idx / 32, k = idx % 32;
    int w = k & 15, hi = k >> 4;
    u64 b = 0;
    for (int l = 0; l < 64; ++l) {
      int i = (hi * 64 + l) * 16 + w;
      if (P.p[25][j * 2048 + i] > 0.0f) b |= (1ull << l);
    }
    g_wfcb[j * 32 + k] = b;
  }
}

// ---------------- single-instruction ballots (inline asm) -------------------
// HIP __ballot(pred) materializes pred (cmp+cndmask+cmp_ne = 3 VALU); these
// emit exactly one v_cmp writing the 64-bit lane mask (exec-masked lanes = 0).
__device__ __forceinline__ u64 ble(int P, int D) {   // ballot(P <= D)
  u64 m;
  asm("v_cmp_le_i32 %0, %1, %2" : "=s"(m) : "v"(P), "v"(D));
  return m;
}
__device__ __forceinline__ u64 bgt0f(float v) {      // ballot(v > 0.0f)
  u64 m;
  asm("v_cmp_lt_f32 %0, 0, %1" : "=s"(m) : "v"(v));
  return m;
}

// ----------------------- fused binary network ------------------------------
// TWO WAVES PER IMAGE (rows 0-2 / 3-5). conv1->conv2->conv3 processed one row
// at a time entirely in wave-uniform registers (ballot results are SGPRs).
// Only conv3's pooled output (consumed cross-wave by conv4) goes to LDS.
struct WaveMem {
  alignas(16) u64 p3s[192];   // conv3+pool out (h*16+pw)*2+chanhalf
  u64 c4s[32];                // conv4 out w*2+chanhalf
};

__global__ __launch_bounds__(256) void fused_kernel(const float* __restrict__ x,
                                                    float* __restrict__ out, int B) {
  const int tid = threadIdx.x;
  const int lane = tid & 63;
  const int wave = tid >> 6;         // 0..3
  const int img = wave >> 1;         // 0..1 within block
  const int half = wave & 1;         // row-half of the image
  const int n = blockIdx.x * 2 + img;
  const bool active = (n < B);

  __shared__ WaveMem wm[2];
  WaveMem& W = wm[img];
  const float* xi = x + (size_t)n * 768;

  if (active) {
    // ---- per-lane constants for conv1..conv3 ----
    const int c1 = lane & 31;
    const bool isSub1 = (lane >= 32);
    const u32 wv = g_w1b[c1];
    const u32 wv2 = wv << 2;
    const int s1v = g_s1[c1];
    const int D0i = (9 - s1v) >> 1;
    const int D0a = (5 - s1v + 2 * __popc(wv & 0x00F)) >> 1;
    const int D0b = (8 - s1v + 2 * __popc(wv & 0x100)) >> 1;
    const int D1a = (7 - s1v + 2 * __popc(wv & 0x003)) >> 1;
    const int D1b = (6 - s1v + 2 * __popc(wv & 0x1C0)) >> 1;
    const u64 fl1 = g_flip1;

    const u32 w0m = g_w2b[lane * 3 + 0];
    const u32 w1m = g_w2b[lane * 3 + 1];
    const u32 w2m = g_w2b[lane * 3 + 2];
    const int s2v = g_s2[lane];
    const int D96h = (96 - s2v) >> 1, D64h = (64 - s2v) >> 1;
    const u64 fl2 = g_flip2;

    const u32* w3p = (const u32*)g_w3b;
    const u32 wl0l = w3p[(lane * 3 + 0) * 2], wl0h = w3p[(lane * 3 + 0) * 2 + 1];
    const u32 wl1l = w3p[(lane * 3 + 1) * 2], wl1h = w3p[(lane * 3 + 1) * 2 + 1];
    const u32 wl2l = w3p[(lane * 3 + 2) * 2], wl2h = w3p[(lane * 3 + 2) * 2 + 1];
    const u32 wh0l = w3p[((64 + lane) * 3 + 0) * 2], wh0h = w3p[((64 + lane) * 3 + 0) * 2 + 1];
    const u32 wh1l = w3p[((64 + lane) * 3 + 1) * 2], wh1h = w3p[((64 + lane) * 3 + 1) * 2 + 1];
    const u32 wh2l = w3p[((64 + lane) * 3 + 2) * 2], wh2h = w3p[((64 + lane) * 3 + 2) * 2 + 1];
    const int sa = g_s3[lane], sb = g_s3[64 + lane];
    const int Da192h = (192 - sa) >> 1, Da128h = (128 - sa) >> 1;
    const int Db192h = (192 - sb) >> 1, Db128h = (128 - sb) >> 1;
    const u64 f3a = g_flip3[0], f3b = g_flip3[1];

    // ---- process this wave's 3 rows ----
    #pragma unroll
    for (int hl = 0; hl < 3; ++hl) {
      const int h = half * 3 + hl;
      // stage A: binarize row into padded (<<4) form; all wave-uniform
      float v0 = xi[h * 128 + lane];
      float v1 = xi[h * 128 + 64 + lane];
      u64 m0 = bgt0f(v0);
      u64 m1 = bgt0f(v1);
      const u64 ra = m0 << 4;
      const u64 rb = (m0 >> 60) | (m1 << 4);
      const u64 rc = m1 >> 60;

      // conv1 + sign + pool: 16 ballots -> a64[j] covers pooled pos 2j,2j+1
      u64 a64[16];
      #pragma unroll
      for (int j = 0; j < 16; ++j) {
        u64 lo = (j < 8) ? ra : rb;
        u64 hi = (j < 8) ? rb : rc;
        const int sh = (8 * j) & 63;
        u64 Wq = (lo >> sh) | ((hi << 1) << (63 - sh));   // 15-bit superwindow
        u32 W0 = (u32)Wq & 0x7FF;
        u32 W1 = ((u32)Wq >> 4) & 0x7FF;
        u32 Wv = isSub1 ? W1 : W0;       // sub0 half: pooled 2j; sub1: 2j+1
        int P0 = __popc((Wv ^ wv) & 0x1FF);
        int P1 = __popc((Wv ^ wv2) & 0x7FC);
        int D0 = D0i, D1 = D0i;
        if (j == 0)  { D0 = isSub1 ? D0i : D0a; D1 = isSub1 ? D0i : D1a; }
        if (j == 15) { D0 = isSub1 ? D0b : D0i; D1 = isSub1 ? D1b : D0i; }
        a64[j] = (ble(P0, D0) ^ fl1) | (ble(P1, D1) ^ fl1);
      }

      // u32 view of pooled row (static index -> SALU extract)
      auto AW = [&](int w) -> u32 {
        u64 v = a64[w >> 1];
        return (w & 1) ? (u32)(v >> 32) : (u32)v;
      };
      // conv2 (32->64, k=3, pad1) + sign: one v_cmp per position
      auto CONV2 = [&](int w, u32 am, u32 ac, u32 ap) -> u64 {
        int P, D;
        if (w == 0)       { P = __popc(ac ^ w1m) + __popc(ap ^ w2m); D = D64h; }
        else if (w == 31) { P = __popc(am ^ w0m) + __popc(ac ^ w1m); D = D64h; }
        else { P = __popc(am ^ w0m) + __popc(ac ^ w1m) + __popc(ap ^ w2m); D = D96h; }
        return ble(P, D) ^ fl2;
      };
      // conv3 (64->128, k=3, pad1) + sign + pool; kind: 0=pw0, 1=mid, 2=pw15
      auto CONV3 = [&](int kind, u64 Au, u64 Bu, u64 Cu, u64 Du, int pt) {
        u32 Al = (u32)Au, Ah = (u32)(Au >> 32);
        u32 Bl = (u32)Bu, Bh = (u32)(Bu >> 32);
        u32 Cl = (u32)Cu, Ch = (u32)(Cu >> 32);
        u32 Dl = (u32)Du, Dh = (u32)(Du >> 32);
        int P0a, P1a, P0b, P1b, E0a, E1a, E0b, E1b;
        if (kind == 0) {       // out0 short (B,C taps1,2), out1 full (B,C,D)
          P0a = __popc(Bl^wl1l)+__popc(Bh^wl1h)+__popc(Cl^wl2l)+__popc(Ch^wl2h);
          P1a = __popc(Bl^wl0l)+__popc(Bh^wl0h)+__popc(Cl^wl1l)+__popc(Ch^wl1h)
              + __popc(Dl^wl2l)+__popc(Dh^wl2h);
          P0b = __popc(Bl^wh1l)+__popc(Bh^wh1h)+__popc(Cl^wh2l)+__popc(Ch^wh2h);
          P1b = __popc(Bl^wh0l)+__popc(Bh^wh0h)+__popc(Cl^wh1l)+__popc(Ch^wh1h)
              + __popc(Dl^wh2l)+__popc(Dh^wh2h);
          E0a = Da128h; E1a = Da192h; E0b = Db128h; E1b = Db192h;
        } else if (kind == 2) { // out0 full (A,B,C), out1 short (B,C taps0,1)
          P0a = __popc(Al^wl0l)+__popc(Ah^wl0h)+__popc(Bl^wl1l)+__popc(Bh^wl1h)
              + __popc(Cl^wl2l)+__popc(Ch^wl2h);
          P1a = __popc(Bl^wl0l)+__popc(Bh^wl0h)+__popc(Cl^wl1l)+__popc(Ch^wl1h);
          P0b = __popc(Al^wh0l)+__popc(Ah^wh0h)+__popc(Bl^wh1l)+__popc(Bh^wh1h)
              + __popc(Cl^wh2l)+__popc(Ch^wh2h);
          P1b = __popc(Bl^wh0l)+__popc(Bh^wh0h)+__popc(Cl^wh1l)+__popc(Ch^wh1h);
          E0a = Da192h; E1a = Da128h; E0b = Db192h; E1b = Db128h;
        } else {
          P0a = __popc(Al^wl0l)+__popc(Ah^wl0h)+__popc(Bl^wl1l)+__popc(Bh^wl1h)
              + __popc(Cl^wl2l)+__popc(Ch^wl2h);
          P1a = __popc(Bl^wl0l)+__popc(Bh^wl0h)+__popc(Cl^wl1l)+__popc(Ch^wl1h)
              + __popc(Dl^wl2l)+__popc(Dh^wl2h);
          P0b = __popc(Al^wh0l)+__popc(Ah^wh0h)+__popc(Bl^wh1l)+__popc(Bh^wh1h)
              + __popc(Cl^wh2l)+__popc(Ch^wh2h);
          P1b = __popc(Bl^wh0l)+__popc(Bh^wh0h)+__popc(Cl^wh1l)+__popc(Ch^wh1h)
              + __popc(Dl^wh2l)+__popc(Dh^wh2h);
          E0a = Da192h; E1a = Da192h; E0b = Db192h; E1b = Db192h;
        }
        u64 mm0 = (ble(P0a, E0a) ^ f3a) | (ble(P1a, E1a) ^ f3a);
        u64 mm1 = (ble(P0b, E0b) ^ f3b) | (ble(P1b, E1b) ^ f3b);
        if (lane == 0) { W.p3s[2 * pt] = mm0; W.p3s[2 * pt + 1] = mm1; }
      };

      const int pt0 = h * 16;
      // software-pipelined conv2 -> conv3 over the row
      u64 cw0 = CONV2(0, AW(0), AW(0), AW(1));
      u64 cw1 = CONV2(1, AW(0), AW(1), AW(2));
      u64 cw2 = CONV2(2, AW(1), AW(2), AW(3));
      CONV3(0, cw0, cw0, cw1, cw2, pt0);           // pw=0: B=c2[0],C=c2[1],D=c2[2]
      u64 Ar = cw1, Br = cw2;                      // c2[2pw-1], c2[2pw] for pw=1
      #pragma unroll
      for (int pw = 1; pw <= 14; ++pw) {
        u64 Cr = CONV2(2 * pw + 1, AW(2 * pw), AW(2 * pw + 1), AW(2 * pw + 2));
        u64 Dr = CONV2(2 * pw + 2, AW(2 * pw + 1), AW(2 * pw + 2), AW(2 * pw + 3));
        CONV3(1, Ar, Br, Cr, Dr, pt0 + pw);
        Ar = Cr; Br = Dr;
      }
      u64 C15 = CONV2(31, AW(30), AW(31), AW(31));
      CONV3(2, Ar, Br, C15, C15, pt0 + 15);        // pw=15: A=c2[29],B=c2[30],C=c2[31]
    }
  }

  __syncthreads();   // conv4 mixes rows across the two waves

  if (active) {
    // ---- conv4 (128->128, k=(6,1)) + sign — split by output-channel half ----
    const u32* w4 = (const u32*)g_w4b;
    const int c = half * 64 + lane;
    u32 wt[24];
    #pragma unroll
    for (int h = 0; h < 6; ++h) {
      wt[h * 4 + 0] = w4[(c * 6 + h) * 4 + 0];
      wt[h * 4 + 1] = w4[(c * 6 + h) * 4 + 1];
      wt[h * 4 + 2] = w4[(c * 6 + h) * 4 + 2];
      wt[h * 4 + 3] = w4[(c * 6 + h) * 4 + 3];
    }
    const int Dch = (768 - g_s4[c]) >> 1;
    const u64 fl4 = half ? g_flip4[1] : g_flip4[0];
    #pragma unroll 2
    for (int w = 0; w < 16; ++w) {
      int acc = 0;
      #pragma unroll
      for (int h = 0; h < 6; ++h) {
        const u32* p = (const u32*)&W.p3s[(h * 16 + w) * 2];
        acc += __popc(p[0] ^ wt[h * 4 + 0]) + __popc(p[1] ^ wt[h * 4 + 1])
             + __popc(p[2] ^ wt[h * 4 + 2]) + __popc(p[3] ^ wt[h * 4 + 3]);
      }
      u64 m = ble(acc, Dch) ^ fl4;
      if (lane == 0) W.c4s[2 * w + half] = m;
    }
  }

  __syncthreads();   // FC reads both channel halves

  if (active && half == 0) {
    // ---- FC: sign(h) . sign(wfc)^T + bfc  (shuffle reduce) ----
    const int k = lane & 31, hf = lane >> 5;
    u64 hw = W.c4s[(k & 15) * 2 + (k >> 4)];
    #pragma unroll
    for (int it = 0; it < 3; ++it) {
      int j = 2 * it + hf;
      int pc = __popcll(hw ^ g_wfcb[j * 32 + k]);
      pc += __shfl_xor(pc, 16);
      pc += __shfl_xor(pc, 8);
      pc += __shfl_xor(pc, 4);
      pc += __shfl_xor(pc, 2);
      pc += __shfl_xor(pc, 1);
      if (k == 0)
        out[(size_t)n * 6 + j] = __fadd_rn((float)(2048 - 2 * pc), g_bfc[j]);
    }
  }
}

// ------------------------------ launch --------------------------------------
extern "C" void kernel_launch(void* const* d_in, const int* in_sizes, int n_in,
                              void* d_out, int out_size, void* d_ws, size_t ws_size,
                              hipStream_t stream) {
  (void)d_ws; (void)ws_size; (void)n_in;
  Ptrs P;
  for (int i = 0; i < 27; ++i) P.p[i] = (const float*)d_in[i];

  hipLaunchKernelGGL(prepack_kernel, dim3(11), dim3(256), 0, stream, P);

  const float* x = (const float*)d_in[0];
  float* out = (float*)d_out;
  int B = in_sizes[0] / 768;                 // 4096
  hipLaunchKernelGGL(fused_kernel, dim3((B + 1) / 2), dim3(256), 0, stream, x, out, B);
}

// Round 10
// 83.264 us; speedup vs baseline: 1.2700x; 1.0159x over previous
//
#include <hip/hip_runtime.h>

typedef unsigned long long u64;
typedef unsigned int u32;

// ---------------- packed weights / integer thresholds (device globals) ------
// Layers 2/3/4: BN-decreasing ("flipped") channels are stored with
// COMPLEMENTED weight bits and threshold s -> 1-s, which is exactly
// equivalent (T_bits == T for all their windows). Only conv1 keeps a
// runtime flip mask (its edge corrections are weight-dependent).
__device__ u32 g_w1b[32];                 // 9 taps in low bits
__device__ u32 g_w2b[64 * 3];             // [c][k], bit = cin (0..31)
__device__ u64 g_w3b[128 * 3];            // [c][k], bit = cin (0..63)
__device__ u64 g_w4b[128 * 6 * 2];        // [c][h][hi], bit l = cin hi*64+l
__device__ u64 g_wfcb[6 * 32];            // [j][k]: w=k%16, hi=k/16, bit l -> i=(hi*64+l)*16+w
__device__ float g_bfc[6];

__device__ int g_s1[32], g_s2[64], g_s3[128], g_s4[128];   // integer S-thresholds
__device__ u64 g_flip1;                                     // conv1 flip mask

struct Ptrs { const float* p[27]; };

// exact f32 op order of the np reference: y = ((S + b) * inv) + t, no FMA
__device__ __forceinline__ int predS(int S, float b, float inv, float t) {
  float hv = __fadd_rn((float)S, b);
  float y = __fadd_rn(__fmul_rn(hv, inv), t);
  return y > 0.0f;
}

__device__ __forceinline__ void bn_fold(float b, float g, float be, float m, float v,
                                        float* ob, float* oinv, float* ot) {
  double iv = (double)g * (1.0 / sqrt((double)v + 1e-5));
  float invf = (float)iv;
  *ob = b;
  *oinv = invf;
  *ot = __fadd_rn(be, -__fmul_rn(m, invf));
}

// pred(S) == (S >= smin) XOR flip, exactly, for all integer S in range.
__device__ __forceinline__ void find_thr(float bias, float g, float be, float m, float v,
                                         int* smin, int* flip) {
  float b, inv, t;
  bn_fold(bias, g, be, m, v, &b, &inv, &t);
  int pl = predS(-2048, b, inv, t), ph = predS(2048, b, inv, t);
  if (pl && ph) { *smin = -4096; *flip = 0; }
  else if (!pl && !ph) { *smin = 4096; *flip = 0; }
  else if (!pl && ph) {
    int lo = -2048, hi = 2048;
    while (hi - lo > 1) { int md = (lo + hi) >> 1; if (predS(md, b, inv, t)) hi = md; else lo = md; }
    *smin = hi; *flip = 0;
  } else {
    int lo = -2048, hi = 2048;
    while (hi - lo > 1) { int md = (lo + hi) >> 1; if (predS(md, b, inv, t)) lo = md; else hi = md; }
    *smin = lo + 1; *flip = 1;
  }
}

// -------------------------- weight prepack ---------------------------------
__global__ __launch_bounds__(256) void prepack_kernel(Ptrs P) {
  int tid = threadIdx.x;
  int gid = blockIdx.x * 256 + tid;
  if (gid < 32) {                                   // conv1 thresholds (+flip mask)
    int c = gid, smin, flip;
    find_thr(P.p[2][c], P.p[3][c], P.p[4][c], P.p[5][c], P.p[6][c], &smin, &flip);
    g_s1[c] = smin;
    u64 fl = __ballot(flip != 0);
    if (c == 0) g_flip1 = (fl & 0xFFFFFFFFULL) | (fl << 32);
  } else if (gid >= 64 && gid < 128) {              // conv2 thresholds (flip folded)
    int c = gid - 64, smin, flip;
    find_thr(P.p[8][c], P.p[9][c], P.p[10][c], P.p[11][c], P.p[12][c], &smin, &flip);
    g_s2[c] = flip ? 1 - smin : smin;
  } else if (gid >= 128 && gid < 256) {             // conv3 thresholds
    int c = gid - 128, smin, flip;
    find_thr(P.p[14][c], P.p[15][c], P.p[16][c], P.p[17][c], P.p[18][c], &smin, &flip);
    g_s3[c] = flip ? 1 - smin : smin;
  } else if (gid >= 256 && gid < 384) {             // conv4 thresholds
    int c = gid - 256, smin, flip;
    find_thr(P.p[20][c], P.p[21][c], P.p[22][c], P.p[23][c], P.p[24][c], &smin, &flip);
    g_s4[c] = flip ? 1 - smin : smin;
  } else if (gid >= 384 && gid < 416) {             // w1 bits (flip NOT folded)
    int c = gid - 384;
    u32 b = 0;
    for (int k = 0; k < 9; ++k)
      if (P.p[1][c * 9 + k] > 0.0f) b |= (1u << k);
    g_w1b[c] = b;
  } else if (gid >= 416 && gid < 422) {
    g_bfc[gid - 416] = P.p[26][gid - 416];
  } else if (gid >= 512 && gid < 704) {             // w2 bits (complement if flip)
    int idx = gid - 512;
    int c = idx / 3, k = idx % 3;
    int smin, flip;
    find_thr(P.p[8][c], P.p[9][c], P.p[10][c], P.p[11][c], P.p[12][c], &smin, &flip);
    u32 b = 0;
    for (int cin = 0; cin < 32; ++cin)
      if (P.p[7][(c * 32 + cin) * 3 + k] > 0.0f) b |= (1u << cin);
    g_w2b[c * 3 + k] = flip ? ~b : b;
  } else if (gid >= 704 && gid < 1088) {            // w3 bits (complement if flip)
    int idx = gid - 704;
    int c = idx / 3, k = idx % 3;
    int smin, flip;
    find_thr(P.p[14][c], P.p[15][c], P.p[16][c], P.p[17][c], P.p[18][c], &smin, &flip);
    u64 b = 0;
    for (int cin = 0; cin < 64; ++cin)
      if (P.p[13][(c * 64 + cin) * 3 + k] > 0.0f) b |= (1ull << cin);
    g_w3b[c * 3 + k] = flip ? ~b : b;
  } else if (gid >= 1088 && gid < 2624) {           // w4 bits (complement if flip)
    int idx = gid - 1088;
    int c = idx / 12, r = idx % 12, h = r >> 1, hi = r & 1;
    int smin, flip;
    find_thr(P.p[20][c], P.p[21][c], P.p[22][c], P.p[23][c], P.p[24][c], &smin, &flip);
    u64 b = 0;
    for (int l = 0; l < 64; ++l) {
      int cin = hi * 64 + l;
      if (P.p[19][(c * 128 + cin) * 6 + h] > 0.0f) b |= (1ull << l);
    }
    g_w4b[(c * 6 + h) * 2 + hi] = flip ? ~b : b;
  } else if (gid >= 2624 && gid < 2816) {           // wfc bits (no BN)
    int idx = gid - 2624;
    int j = idx / 32, k = idx % 32;
    int w = k & 15, hi = k >> 4;
    u64 b = 0;
    for (int l = 0; l < 64; ++l) {
      int i = (hi * 64 + l) * 16 + w;
      if (P.p[25][j * 2048 + i] > 0.0f) b |= (1ull << l);
    }
    g_wfcb[j * 32 + k] = b;
  }
}

// ---------------- single-instruction ballots (inline asm) -------------------
__device__ __forceinline__ u64 ble(int P, int D) {   // ballot(P <= D)
  u64 m;
  asm("v_cmp_le_i32 %0, %1, %2" : "=s"(m) : "v"(P), "v"(D));
  return m;
}
__device__ __forceinline__ u64 bgt0f(float v) {      // ballot(v > 0.0f)
  u64 m;
  asm("v_cmp_lt_f32 %0, 0, %1" : "=s"(m) : "v"(v));
  return m;
}

// ----------------------- fused binary network ------------------------------
// TWO WAVES PER IMAGE (rows 0-2 / 3-5). conv1->conv2->conv3 processed one row
// at a time entirely in wave-uniform registers (ballot results are SGPRs).
// Only conv3's pooled output (consumed cross-wave by conv4) goes to LDS.
struct WaveMem {
  alignas(16) u64 p3s[192];   // conv3+pool out (h*16+pw)*2+chanhalf
  u64 c4s[32];                // conv4 out w*2+chanhalf
};

__global__ __launch_bounds__(256) void fused_kernel(const float* __restrict__ x,
                                                    float* __restrict__ out, int B) {
  const int tid = threadIdx.x;
  const int lane = tid & 63;
  const int wave = tid >> 6;         // 0..3
  const int img = wave >> 1;         // 0..1 within block
  const int half = wave & 1;         // row-half of the image
  const int n = blockIdx.x * 2 + img;
  const bool active = (n < B);

  __shared__ WaveMem wm[2];
  WaveMem& W = wm[img];
  const float* xi = x + (size_t)n * 768;

  if (active) {
    // ---- per-lane constants for conv1..conv3 ----
    const int c1 = lane & 31;
    const bool isSub1 = (lane >= 32);
    const u32 wv = g_w1b[c1];
    const u32 wv2 = wv << 2;
    const int s1v = g_s1[c1];
    const int D0i = (9 - s1v) >> 1;
    const int D0a = (5 - s1v + 2 * __popc(wv & 0x00F)) >> 1;
    const int D0b = (8 - s1v + 2 * __popc(wv & 0x100)) >> 1;
    const int D1a = (7 - s1v + 2 * __popc(wv & 0x003)) >> 1;
    const int D1b = (6 - s1v + 2 * __popc(wv & 0x1C0)) >> 1;
    const u64 fl1 = g_flip1;

    const u32 w0m = g_w2b[lane * 3 + 0];
    const u32 w1m = g_w2b[lane * 3 + 1];
    const u32 w2m = g_w2b[lane * 3 + 2];
    const int s2v = g_s2[lane];
    const int D96h = (96 - s2v) >> 1, D64h = (64 - s2v) >> 1;

    const u32* w3p = (const u32*)g_w3b;
    const u32 wl0l = w3p[(lane * 3 + 0) * 2], wl0h = w3p[(lane * 3 + 0) * 2 + 1];
    const u32 wl1l = w3p[(lane * 3 + 1) * 2], wl1h = w3p[(lane * 3 + 1) * 2 + 1];
    const u32 wl2l = w3p[(lane * 3 + 2) * 2], wl2h = w3p[(lane * 3 + 2) * 2 + 1];
    const u32 wh0l = w3p[((64 + lane) * 3 + 0) * 2], wh0h = w3p[((64 + lane) * 3 + 0) * 2 + 1];
    const u32 wh1l = w3p[((64 + lane) * 3 + 1) * 2], wh1h = w3p[((64 + lane) * 3 + 1) * 2 + 1];
    const u32 wh2l = w3p[((64 + lane) * 3 + 2) * 2], wh2h = w3p[((64 + lane) * 3 + 2) * 2 + 1];
    const int sa = g_s3[lane], sb = g_s3[64 + lane];
    const int Da192h = (192 - sa) >> 1, Da128h = (128 - sa) >> 1;
    const int Db192h = (192 - sb) >> 1, Db128h = (128 - sb) >> 1;

    // ---- process this wave's 3 rows ----
    #pragma unroll
    for (int hl = 0; hl < 3; ++hl) {
      const int h = half * 3 + hl;
      // stage A: binarize row into padded (<<4) form; all wave-uniform
      float v0 = xi[h * 128 + lane];
      float v1 = xi[h * 128 + 64 + lane];
      u64 m0 = bgt0f(v0);
      u64 m1 = bgt0f(v1);
      const u64 ra = m0 << 4;
      const u64 rb = (m0 >> 60) | (m1 << 4);
      const u64 rc = m1 >> 60;

      // conv1 + sign + pool: 16 ballots -> a64[j] covers pooled pos 2j,2j+1
      u64 a64[16];
      #pragma unroll
      for (int j = 0; j < 16; ++j) {
        u64 lo = (j < 8) ? ra : rb;
        u64 hi = (j < 8) ? rb : rc;
        const int sh = (8 * j) & 63;
        u64 Wq = (lo >> sh) | ((hi << 1) << (63 - sh));   // 15-bit superwindow
        u32 W0 = (u32)Wq & 0x7FF;
        u32 W1 = ((u32)Wq >> 4) & 0x7FF;
        u32 Wv = isSub1 ? W1 : W0;       // sub0 half: pooled 2j; sub1: 2j+1
        int P0 = __popc((Wv ^ wv) & 0x1FF);
        int P1 = __popc((Wv ^ wv2) & 0x7FC);
        int D0 = D0i, D1 = D0i;
        if (j == 0)  { D0 = isSub1 ? D0i : D0a; D1 = isSub1 ? D0i : D1a; }
        if (j == 15) { D0 = isSub1 ? D0b : D0i; D1 = isSub1 ? D1b : D0i; }
        a64[j] = (ble(P0, D0) ^ fl1) | (ble(P1, D1) ^ fl1);
      }

      // u32 view of pooled row (static index -> SALU extract)
      auto AW = [&](int w) -> u32 {
        u64 v = a64[w >> 1];
        return (w & 1) ? (u32)(v >> 32) : (u32)v;
      };
      // conv2 (32->64, k=3, pad1) + sign: one v_cmp per position
      auto CONV2 = [&](int w, u32 am, u32 ac, u32 ap) -> u64 {
        int P, D;
        if (w == 0)       { P = __popc(ac ^ w1m) + __popc(ap ^ w2m); D = D64h; }
        else if (w == 31) { P = __popc(am ^ w0m) + __popc(ac ^ w1m); D = D64h; }
        else { P = __popc(am ^ w0m) + __popc(ac ^ w1m) + __popc(ap ^ w2m); D = D96h; }
        return ble(P, D);
      };
      // conv3 (64->128, k=3, pad1) + sign + pool; kind: 0=pw0, 1=mid, 2=pw15
      auto CONV3 = [&](int kind, u64 Au, u64 Bu, u64 Cu, u64 Du, int pt) {
        u32 Al = (u32)Au, Ah = (u32)(Au >> 32);
        u32 Bl = (u32)Bu, Bh = (u32)(Bu >> 32);
        u32 Cl = (u32)Cu, Ch = (u32)(Cu >> 32);
        u32 Dl = (u32)Du, Dh = (u32)(Du >> 32);
        int P0a, P1a, P0b, P1b, E0a, E1a, E0b, E1b;
        if (kind == 0) {       // out0 short (B,C taps1,2), out1 full (B,C,D)
          P0a = __popc(Bl^wl1l)+__popc(Bh^wl1h)+__popc(Cl^wl2l)+__popc(Ch^wl2h);
          P1a = __popc(Bl^wl0l)+__popc(Bh^wl0h)+__popc(Cl^wl1l)+__popc(Ch^wl1h)
              + __popc(Dl^wl2l)+__popc(Dh^wl2h);
          P0b = __popc(Bl^wh1l)+__popc(Bh^wh1h)+__popc(Cl^wh2l)+__popc(Ch^wh2h);
          P1b = __popc(Bl^wh0l)+__popc(Bh^wh0h)+__popc(Cl^wh1l)+__popc(Ch^wh1h)
              + __popc(Dl^wh2l)+__popc(Dh^wh2h);
          E0a = Da128h; E1a = Da192h; E0b = Db128h; E1b = Db192h;
        } else if (kind == 2) { // out0 full (A,B,C), out1 short (B,C taps0,1)
          P0a = __popc(Al^wl0l)+__popc(Ah^wl0h)+__popc(Bl^wl1l)+__popc(Bh^wl1h)
              + __popc(Cl^wl2l)+__popc(Ch^wl2h);
          P1a = __popc(Bl^wl0l)+__popc(Bh^wl0h)+__popc(Cl^wl1l)+__popc(Ch^wl1h);
          P0b = __popc(Al^wh0l)+__popc(Ah^wh0h)+__popc(Bl^wh1l)+__popc(Bh^wh1h)
              + __popc(Cl^wh2l)+__popc(Ch^wh2h);
          P1b = __popc(Bl^wh0l)+__popc(Bh^wh0h)+__popc(Cl^wh1l)+__popc(Ch^wh1h);
          E0a = Da192h; E1a = Da128h; E0b = Db192h; E1b = Db128h;
        } else {
          P0a = __popc(Al^wl0l)+__popc(Ah^wl0h)+__popc(Bl^wl1l)+__popc(Bh^wl1h)
              + __popc(Cl^wl2l)+__popc(Ch^wl2h);
          P1a = __popc(Bl^wl0l)+__popc(Bh^wl0h)+__popc(Cl^wl1l)+__popc(Ch^wl1h)
              + __popc(Dl^wl2l)+__popc(Dh^wl2h);
          P0b = __popc(Al^wh0l)+__popc(Ah^wh0h)+__popc(Bl^wh1l)+__popc(Bh^wh1h)
              + __popc(Cl^wh2l)+__popc(Ch^wh2h);
          P1b = __popc(Bl^wh0l)+__popc(Bh^wh0h)+__popc(Cl^wh1l)+__popc(Ch^wh1h)
              + __popc(Dl^wh2l)+__popc(Dh^wh2h);
          E0a = Da192h; E1a = Da192h; E0b = Db192h; E1b = Db192h;
        }
        u64 mm0 = ble(P0a, E0a) | ble(P1a, E1a);
        u64 mm1 = ble(P0b, E0b) | ble(P1b, E1b);
        if (lane == 0) { W.p3s[2 * pt] = mm0; W.p3s[2 * pt + 1] = mm1; }
      };

      const int pt0 = h * 16;
      // software-pipelined conv2 -> conv3 over the row
      u64 cw0 = CONV2(0, AW(0), AW(0), AW(1));
      u64 cw1 = CONV2(1, AW(0), AW(1), AW(2));
      u64 cw2 = CONV2(2, AW(1), AW(2), AW(3));
      CONV3(0, cw0, cw0, cw1, cw2, pt0);           // pw=0: B=c2[0],C=c2[1],D=c2[2]
      u64 Ar = cw1, Br = cw2;                      // c2[2pw-1], c2[2pw] for pw=1
      #pragma unroll
      for (int pw = 1; pw <= 14; ++pw) {
        u64 Cr = CONV2(2 * pw + 1, AW(2 * pw), AW(2 * pw + 1), AW(2 * pw + 2));
        u64 Dr = CONV2(2 * pw + 2, AW(2 * pw + 1), AW(2 * pw + 2), AW(2 * pw + 3));
        CONV3(1, Ar, Br, Cr, Dr, pt0 + pw);
        Ar = Cr; Br = Dr;
      }
      u64 C15 = CONV2(31, AW(30), AW(31), AW(31));
      CONV3(2, Ar, Br, C15, C15, pt0 + 15);        // pw=15: A=c2[29],B=c2[30],C=c2[31]
    }
  }

  __syncthreads();   // conv4 mixes rows across the two waves

  if (active) {
    // ---- conv4 (128->128, k=(6,1)) + sign — split by output-channel half ----
    const u32* w4 = (const u32*)g_w4b;
    const int c = half * 64 + lane;
    u32 wt[24];
    #pragma unroll
    for (int h = 0; h < 6; ++h) {
      wt[h * 4 + 0] = w4[(c * 6 + h) * 4 + 0];
      wt[h * 4 + 1] = w4[(c * 6 + h) * 4 + 1];
      wt[h * 4 + 2] = w4[(c * 6 + h) * 4 + 2];
      wt[h * 4 + 3] = w4[(c * 6 + h) * 4 + 3];
    }
    const int Dch = (768 - g_s4[c]) >> 1;
    #pragma unroll 2
    for (int w = 0; w < 16; ++w) {
      int acc = 0;
      #pragma unroll
      for (int h = 0; h < 6; ++h) {
        const u32* p = (const u32*)&W.p3s[(h * 16 + w) * 2];
        acc += __popc(p[0] ^ wt[h * 4 + 0]) + __popc(p[1] ^ wt[h * 4 + 1])
             + __popc(p[2] ^ wt[h * 4 + 2]) + __popc(p[3] ^ wt[h * 4 + 3]);
      }
      u64 m = ble(acc, Dch);
      if (lane == 0) W.c4s[2 * w + half] = m;
    }
  }

  __syncthreads();   // FC reads both channel halves

  if (active && half == 0) {
    // ---- FC: sign(h) . sign(wfc)^T + bfc  (shuffle reduce) ----
    const int k = lane & 31, hf = lane >> 5;
    u64 hw = W.c4s[(k & 15) * 2 + (k >> 4)];
    #pragma unroll
    for (int it = 0; it < 3; ++it) {
      int j = 2 * it + hf;
      int pc = __popcll(hw ^ g_wfcb[j * 32 + k]);
      pc += __shfl_xor(pc, 16);
      pc += __shfl_xor(pc, 8);
      pc += __shfl_xor(pc, 4);
      pc += __shfl_xor(pc, 2);
      pc += __shfl_xor(pc, 1);
      if (k == 0)
        out[(size_t)n * 6 + j] = __fadd_rn((float)(2048 - 2 * pc), g_bfc[j]);
    }
  }
}

// ------------------------------ launch --------------------------------------
extern "C" void kernel_launch(void* const* d_in, const int* in_sizes, int n_in,
                              void* d_out, int out_size, void* d_ws, size_t ws_size,
                              hipStream_t stream) {
  (void)d_ws; (void)ws_size; (void)n_in;
  Ptrs P;
  for (int i = 0; i < 27; ++i) P.p[i] = (const float*)d_in[i];

  hipLaunchKernelGGL(prepack_kernel, dim3(11), dim3(256), 0, stream, P);

  const float* x = (const float*)d_in[0];
  float* out = (float*)d_out;
  int B = in_sizes[0] / 768;                 // 4096
  hipLaunchKernelGGL(fused_kernel, dim3((B + 1) / 2), dim3(256), 0, stream, x, out, B);
}

// Round 11
// 75.896 us; speedup vs baseline: 1.3932x; 1.0971x over previous
//
#include <hip/hip_runtime.h>

typedef unsigned long long u64;
typedef unsigned int u32;

// ---------------- packed weights / integer thresholds (device globals) ------
// Layers 2/3/4: BN-decreasing ("flipped") channels are stored with
// COMPLEMENTED weight bits and threshold s -> 1-s (exactly equivalent).
// Only conv1 keeps a runtime flip mask (edge corrections are weight-dep).
__device__ u32 g_w1b[32];                 // 9 taps in low bits
__device__ u32 g_w2b[64 * 3];             // [c][k], bit = cin (0..31)
__device__ u64 g_w3b[128 * 3];            // [c][k], bit = cin (0..63)
__device__ u64 g_w4b[128 * 6 * 2];        // [c][h][hi], bit l = cin hi*64+l
__device__ u64 g_wfcb[6 * 32];            // [j][k]: w=k%16, hi=k/16, bit l -> i=(hi*64+l)*16+w
__device__ float g_bfc[6];

__device__ int g_s1[32], g_s2[64], g_s3[128], g_s4[128];   // integer S-thresholds
__device__ u64 g_flip1;                                     // conv1 flip mask

struct Ptrs { const float* p[27]; };

// exact f32 op order of the np reference: y = ((S + b) * inv) + t, no FMA
__device__ __forceinline__ int predS(int S, float b, float inv, float t) {
  float hv = __fadd_rn((float)S, b);
  float y = __fadd_rn(__fmul_rn(hv, inv), t);
  return y > 0.0f;
}

__device__ __forceinline__ void bn_fold(float b, float g, float be, float m, float v,
                                        float* ob, float* oinv, float* ot) {
  double iv = (double)g * (1.0 / sqrt((double)v + 1e-5));
  float invf = (float)iv;
  *ob = b;
  *oinv = invf;
  *ot = __fadd_rn(be, -__fmul_rn(m, invf));
}

// pred(S) == (S >= smin) XOR flip, exactly, for all integer S in range.
__device__ __forceinline__ void find_thr(float bias, float g, float be, float m, float v,
                                         int* smin, int* flip) {
  float b, inv, t;
  bn_fold(bias, g, be, m, v, &b, &inv, &t);
  int pl = predS(-2048, b, inv, t), ph = predS(2048, b, inv, t);
  if (pl && ph) { *smin = -4096; *flip = 0; }
  else if (!pl && !ph) { *smin = 4096; *flip = 0; }
  else if (!pl && ph) {
    int lo = -2048, hi = 2048;
    while (hi - lo > 1) { int md = (lo + hi) >> 1; if (predS(md, b, inv, t)) hi = md; else lo = md; }
    *smin = hi; *flip = 0;
  } else {
    int lo = -2048, hi = 2048;
    while (hi - lo > 1) { int md = (lo + hi) >> 1; if (predS(md, b, inv, t)) lo = md; else hi = md; }
    *smin = lo + 1; *flip = 1;
  }
}

// -------------------------- weight prepack ---------------------------------
__global__ __launch_bounds__(256) void prepack_kernel(Ptrs P) {
  int tid = threadIdx.x;
  int gid = blockIdx.x * 256 + tid;
  if (gid < 32) {                                   // conv1 thresholds (+flip mask)
    int c = gid, smin, flip;
    find_thr(P.p[2][c], P.p[3][c], P.p[4][c], P.p[5][c], P.p[6][c], &smin, &flip);
    g_s1[c] = smin;
    u64 fl = __ballot(flip != 0);
    if (c == 0) g_flip1 = (fl & 0xFFFFFFFFULL) | (fl << 32);
  } else if (gid >= 64 && gid < 128) {              // conv2 thresholds (flip folded)
    int c = gid - 64, smin, flip;
    find_thr(P.p[8][c], P.p[9][c], P.p[10][c], P.p[11][c], P.p[12][c], &smin, &flip);
    g_s2[c] = flip ? 1 - smin : smin;
  } else if (gid >= 128 && gid < 256) {             // conv3 thresholds
    int c = gid - 128, smin, flip;
    find_thr(P.p[14][c], P.p[15][c], P.p[16][c], P.p[17][c], P.p[18][c], &smin, &flip);
    g_s3[c] = flip ? 1 - smin : smin;
  } else if (gid >= 256 && gid < 384) {             // conv4 thresholds
    int c = gid - 256, smin, flip;
    find_thr(P.p[20][c], P.p[21][c], P.p[22][c], P.p[23][c], P.p[24][c], &smin, &flip);
    g_s4[c] = flip ? 1 - smin : smin;
  } else if (gid >= 384 && gid < 416) {             // w1 bits (flip NOT folded)
    int c = gid - 384;
    u32 b = 0;
    for (int k = 0; k < 9; ++k)
      if (P.p[1][c * 9 + k] > 0.0f) b |= (1u << k);
    g_w1b[c] = b;
  } else if (gid >= 416 && gid < 422) {
    g_bfc[gid - 416] = P.p[26][gid - 416];
  } else if (gid >= 512 && gid < 704) {             // w2 bits (complement if flip)
    int idx = gid - 512;
    int c = idx / 3, k = idx % 3;
    int smin, flip;
    find_thr(P.p[8][c], P.p[9][c], P.p[10][c], P.p[11][c], P.p[12][c], &smin, &flip);
    u32 b = 0;
    for (int cin = 0; cin < 32; ++cin)
      if (P.p[7][(c * 32 + cin) * 3 + k] > 0.0f) b |= (1u << cin);
    g_w2b[c * 3 + k] = flip ? ~b : b;
  } else if (gid >= 704 && gid < 1088) {            // w3 bits (complement if flip)
    int idx = gid - 704;
    int c = idx / 3, k = idx % 3;
    int smin, flip;
    find_thr(P.p[14][c], P.p[15][c], P.p[16][c], P.p[17][c], P.p[18][c], &smin, &flip);
    u64 b = 0;
    for (int cin = 0; cin < 64; ++cin)
      if (P.p[13][(c * 64 + cin) * 3 + k] > 0.0f) b |= (1ull << cin);
    g_w3b[c * 3 + k] = flip ? ~b : b;
  } else if (gid >= 1088 && gid < 2624) {           // w4 bits (complement if flip)
    int idx = gid - 1088;
    int c = idx / 12, r = idx % 12, h = r >> 1, hi = r & 1;
    int smin, flip;
    find_thr(P.p[20][c], P.p[21][c], P.p[22][c], P.p[23][c], P.p[24][c], &smin, &flip);
    u64 b = 0;
    for (int l = 0; l < 64; ++l) {
      int cin = hi * 64 + l;
      if (P.p[19][(c * 128 + cin) * 6 + h] > 0.0f) b |= (1ull << l);
    }
    g_w4b[(c * 6 + h) * 2 + hi] = flip ? ~b : b;
  } else if (gid >= 2624 && gid < 2816) {           // wfc bits (no BN)
    int idx = gid - 2624;
    int j = idx / 32, k = idx % 32;
    int w = k & 15, hi = k >> 4;
    u64 b = 0;
    for (int l = 0; l < 64; ++l) {
      int i = (hi * 64 + l) * 16 + w;
      if (P.p[25][j * 2048 + i] > 0.0f) b |= (1ull << l);
    }
    g_wfcb[j * 32 + k] = b;
  }
}

// ---------------- single-instruction primitives (inline asm) ----------------
__device__ __forceinline__ u64 ble(int P, int D) {   // ballot(P <= D)
  u64 m;
  asm("v_cmp_le_i32 %0, %1, %2" : "=s"(m) : "v"(P), "v"(D));
  return m;
}
__device__ __forceinline__ u64 bgt0f(float v) {      // ballot(v > 0.0f)
  u64 m;
  asm("v_cmp_lt_f32 %0, 0, %1" : "=s"(m) : "v"(v));
  return m;
}
__device__ __forceinline__ int bca(u32 x, int acc) { // acc + popc(x), one VALU
  int d;
  asm("v_bcnt_u32_b32 %0, %1, %2" : "=v"(d) : "v"(x), "v"(acc));
  return d;
}
// 11-bit field extract: (sval >> vshift) & 0x7FF, one VALU (VOP3, 1 SGPR)
__device__ __forceinline__ u32 bfe11(u32 sval, int vsh) {
  u32 d;
  asm("v_bfe_u32 %0, %1, %2, 11" : "=v"(d) : "s"(sval), "v"(vsh));
  return d;
}

// ----------------------- fused binary network ------------------------------
// TWO WAVES PER IMAGE (rows 0-2 / 3-5). conv1->conv2->conv3 processed one row
// at a time entirely in wave-uniform registers (ballot results are SGPRs).
// Only conv3's pooled output (consumed cross-wave by conv4) goes to LDS.
struct WaveMem {
  alignas(16) u64 p3s[192];   // conv3+pool out (h*16+pw)*2+chanhalf
  u64 c4s[32];                // conv4 out w*2+chanhalf
};

__global__ __launch_bounds__(256, 8) void fused_kernel(const float* __restrict__ x,
                                                       float* __restrict__ out, int B) {
  const int tid = threadIdx.x;
  const int lane = tid & 63;
  const int wave = tid >> 6;         // 0..3
  const int img = wave >> 1;         // 0..1 within block
  const int half = wave & 1;         // row-half of the image
  const int n = blockIdx.x * 2 + img;
  const bool active = (n < B);

  __shared__ WaveMem wm[2];
  WaveMem& W = wm[img];
  const float* xi = x + (size_t)n * 768;

  if (active) {
    // ---- per-lane constants for conv1..conv3 ----
    const int c1 = lane & 31;
    const bool isSub1 = (lane >= 32);
    const int vsh = isSub1 ? 4 : 0;    // per-lane window shift (VGPR)
    const u32 wv = g_w1b[c1];
    const u32 wv2 = wv << 2;
    const int s1v = g_s1[c1];
    const int D0i = (9 - s1v) >> 1;
    const int D0a = (5 - s1v + 2 * __popc(wv & 0x00F)) >> 1;
    const int D0b = (8 - s1v + 2 * __popc(wv & 0x100)) >> 1;
    const int D1a = (7 - s1v + 2 * __popc(wv & 0x003)) >> 1;
    const int D1b = (6 - s1v + 2 * __popc(wv & 0x1C0)) >> 1;
    const u64 fl1 = g_flip1;

    const u32 w0m = g_w2b[lane * 3 + 0];
    const u32 w1m = g_w2b[lane * 3 + 1];
    const u32 w2m = g_w2b[lane * 3 + 2];
    const int s2v = g_s2[lane];
    const int D96h = (96 - s2v) >> 1, D64h = (64 - s2v) >> 1;

    const u32* w3p = (const u32*)g_w3b;
    const u32 wl0l = w3p[(lane * 3 + 0) * 2], wl0h = w3p[(lane * 3 + 0) * 2 + 1];
    const u32 wl1l = w3p[(lane * 3 + 1) * 2], wl1h = w3p[(lane * 3 + 1) * 2 + 1];
    const u32 wl2l = w3p[(lane * 3 + 2) * 2], wl2h = w3p[(lane * 3 + 2) * 2 + 1];
    const u32 wh0l = w3p[((64 + lane) * 3 + 0) * 2], wh0h = w3p[((64 + lane) * 3 + 0) * 2 + 1];
    const u32 wh1l = w3p[((64 + lane) * 3 + 1) * 2], wh1h = w3p[((64 + lane) * 3 + 1) * 2 + 1];
    const u32 wh2l = w3p[((64 + lane) * 3 + 2) * 2], wh2h = w3p[((64 + lane) * 3 + 2) * 2 + 1];
    const int sa = g_s3[lane], sb = g_s3[64 + lane];
    const int Da192h = (192 - sa) >> 1, Da128h = (128 - sa) >> 1;
    const int Db192h = (192 - sb) >> 1, Db128h = (128 - sb) >> 1;

    // ---- process this wave's 3 rows ----
    #pragma unroll
    for (int hl = 0; hl < 3; ++hl) {
      const int h = half * 3 + hl;
      // stage A: binarize row into padded (<<4) form; all wave-uniform
      float v0 = xi[h * 128 + lane];
      float v1 = xi[h * 128 + 64 + lane];
      u64 m0 = bgt0f(v0);
      u64 m1 = bgt0f(v1);
      const u64 ra = m0 << 4;
      const u64 rb = (m0 >> 60) | (m1 << 4);
      const u64 rc = m1 >> 60;

      // conv1 + sign + pool: 16 ballots -> a64[j] covers pooled pos 2j,2j+1
      u64 a64[16];
      #pragma unroll
      for (int j = 0; j < 16; ++j) {
        u64 lo = (j < 8) ? ra : rb;
        u64 hi = (j < 8) ? rb : rc;
        const int sh = (8 * j) & 63;
        u64 Wq = (lo >> sh) | ((hi << 1) << (63 - sh));   // 15-bit superwindow
        u32 Wv = bfe11((u32)Wq, vsh);    // sub0: bits 0..10; sub1: bits 4..14
        int P0 = __popc((Wv ^ wv) & 0x1FF);
        int P1 = __popc((Wv ^ wv2) & 0x7FC);
        int D0 = D0i, D1 = D0i;
        if (j == 0)  { D0 = isSub1 ? D0i : D0a; D1 = isSub1 ? D0i : D1a; }
        if (j == 15) { D0 = isSub1 ? D0b : D0i; D1 = isSub1 ? D1b : D0i; }
        a64[j] = (ble(P0, D0) ^ fl1) | (ble(P1, D1) ^ fl1);
      }

      // u32 view of pooled row (static index -> SALU extract)
      auto AW = [&](int w) -> u32 {
        u64 v = a64[w >> 1];
        return (w & 1) ? (u32)(v >> 32) : (u32)v;
      };
      // conv2 (32->64, k=3, pad1) + sign: xor + bcnt-accumulate chains
      auto CONV2 = [&](int w, u32 am, u32 ac, u32 ap) -> u64 {
        int P, D;
        if (w == 0)       { P = bca(ap ^ w2m, __popc(ac ^ w1m)); D = D64h; }
        else if (w == 31) { P = bca(ac ^ w1m, __popc(am ^ w0m)); D = D64h; }
        else { P = bca(ap ^ w2m, bca(ac ^ w1m, __popc(am ^ w0m))); D = D96h; }
        return ble(P, D);
      };
      auto POP4 = [&](u32 a, u32 b, u32 c, u32 d) -> int {
        return bca(d, bca(c, bca(b, __popc(a))));
      };
      auto POP6 = [&](u32 a, u32 b, u32 c, u32 d, u32 e, u32 f) -> int {
        return bca(f, bca(e, bca(d, bca(c, bca(b, __popc(a))))));
      };
      // conv3 (64->128, k=3, pad1) + sign + pool; kind: 0=pw0, 1=mid, 2=pw15
      auto CONV3 = [&](int kind, u64 Au, u64 Bu, u64 Cu, u64 Du, int pt) {
        u32 Al = (u32)Au, Ah = (u32)(Au >> 32);
        u32 Bl = (u32)Bu, Bh = (u32)(Bu >> 32);
        u32 Cl = (u32)Cu, Ch = (u32)(Cu >> 32);
        u32 Dl = (u32)Du, Dh = (u32)(Du >> 32);
        int P0a, P1a, P0b, P1b, E0a, E1a, E0b, E1b;
        if (kind == 0) {       // out0 short (B,C taps1,2), out1 full (B,C,D)
          P0a = POP4(Bl^wl1l, Bh^wl1h, Cl^wl2l, Ch^wl2h);
          P1a = POP6(Bl^wl0l, Bh^wl0h, Cl^wl1l, Ch^wl1h, Dl^wl2l, Dh^wl2h);
          P0b = POP4(Bl^wh1l, Bh^wh1h, Cl^wh2l, Ch^wh2h);
          P1b = POP6(Bl^wh0l, Bh^wh0h, Cl^wh1l, Ch^wh1h, Dl^wh2l, Dh^wh2h);
          E0a = Da128h; E1a = Da192h; E0b = Db128h; E1b = Db192h;
        } else if (kind == 2) { // out0 full (A,B,C), out1 short (B,C taps0,1)
          P0a = POP6(Al^wl0l, Ah^wl0h, Bl^wl1l, Bh^wl1h, Cl^wl2l, Ch^wl2h);
          P1a = POP4(Bl^wl0l, Bh^wl0h, Cl^wl1l, Ch^wl1h);
          P0b = POP6(Al^wh0l, Ah^wh0h, Bl^wh1l, Bh^wh1h, Cl^wh2l, Ch^wh2h);
          P1b = POP4(Bl^wh0l, Bh^wh0h, Cl^wh1l, Ch^wh1h);
          E0a = Da192h; E1a = Da128h; E0b = Db192h; E1b = Db128h;
        } else {
          P0a = POP6(Al^wl0l, Ah^wl0h, Bl^wl1l, Bh^wl1h, Cl^wl2l, Ch^wl2h);
          P1a = POP6(Bl^wl0l, Bh^wl0h, Cl^wl1l, Ch^wl1h, Dl^wl2l, Dh^wl2h);
          P0b = POP6(Al^wh0l, Ah^wh0h, Bl^wh1l, Bh^wh1h, Cl^wh2l, Ch^wh2h);
          P1b = POP6(Bl^wh0l, Bh^wh0h, Cl^wh1l, Ch^wh1h, Dl^wh2l, Dh^wh2h);
          E0a = Da192h; E1a = Da192h; E0b = Db192h; E1b = Db192h;
        }
        u64 mm0 = ble(P0a, E0a) | ble(P1a, E1a);
        u64 mm1 = ble(P0b, E0b) | ble(P1b, E1b);
        if (lane == 0) { W.p3s[2 * pt] = mm0; W.p3s[2 * pt + 1] = mm1; }
      };

      const int pt0 = h * 16;
      // software-pipelined conv2 -> conv3 over the row
      u64 cw0 = CONV2(0, AW(0), AW(0), AW(1));
      u64 cw1 = CONV2(1, AW(0), AW(1), AW(2));
      u64 cw2 = CONV2(2, AW(1), AW(2), AW(3));
      CONV3(0, cw0, cw0, cw1, cw2, pt0);           // pw=0: B=c2[0],C=c2[1],D=c2[2]
      u64 Ar = cw1, Br = cw2;                      // c2[2pw-1], c2[2pw] for pw=1
      #pragma unroll
      for (int pw = 1; pw <= 14; ++pw) {
        u64 Cr = CONV2(2 * pw + 1, AW(2 * pw), AW(2 * pw + 1), AW(2 * pw + 2));
        u64 Dr = CONV2(2 * pw + 2, AW(2 * pw + 1), AW(2 * pw + 2), AW(2 * pw + 3));
        CONV3(1, Ar, Br, Cr, Dr, pt0 + pw);
        Ar = Cr; Br = Dr;
      }
      u64 C15 = CONV2(31, AW(30), AW(31), AW(31));
      CONV3(2, Ar, Br, C15, C15, pt0 + 15);        // pw=15: A=c2[29],B=c2[30],C=c2[31]
    }
  }

  __syncthreads();   // conv4 mixes rows across the two waves

  if (active) {
    // ---- conv4 (128->128, k=(6,1)) + sign — split by output-channel half ----
    const u32* w4 = (const u32*)g_w4b;
    const int c = half * 64 + lane;
    u32 wt[24];
    #pragma unroll
    for (int h = 0; h < 6; ++h) {
      wt[h * 4 + 0] = w4[(c * 6 + h) * 4 + 0];
      wt[h * 4 + 1] = w4[(c * 6 + h) * 4 + 1];
      wt[h * 4 + 2] = w4[(c * 6 + h) * 4 + 2];
      wt[h * 4 + 3] = w4[(c * 6 + h) * 4 + 3];
    }
    const int Dch = (768 - g_s4[c]) >> 1;
    #pragma unroll 2
    for (int w = 0; w < 16; ++w) {
      const u32* p0 = (const u32*)&W.p3s[(0 * 16 + w) * 2];
      int acc = __popc(p0[0] ^ wt[0]);
      acc = bca(p0[1] ^ wt[1], acc);
      acc = bca(p0[2] ^ wt[2], acc);
      acc = bca(p0[3] ^ wt[3], acc);
      #pragma unroll
      for (int h = 1; h < 6; ++h) {
        const u32* p = (const u32*)&W.p3s[(h * 16 + w) * 2];
        acc = bca(p[0] ^ wt[h * 4 + 0], acc);
        acc = bca(p[1] ^ wt[h * 4 + 1], acc);
        acc = bca(p[2] ^ wt[h * 4 + 2], acc);
        acc = bca(p[3] ^ wt[h * 4 + 3], acc);
      }
      u64 m = ble(acc, Dch);
      if (lane == 0) W.c4s[2 * w + half] = m;
    }
  }

  __syncthreads();   // FC reads both channel halves

  if (active && half == 0) {
    // ---- FC: sign(h) . sign(wfc)^T + bfc  (shuffle reduce) ----
    const int k = lane & 31, hf = lane >> 5;
    u64 hw = W.c4s[(k & 15) * 2 + (k >> 4)];
    #pragma unroll
    for (int it = 0; it < 3; ++it) {
      int j = 2 * it + hf;
      int pc = __popcll(hw ^ g_wfcb[j * 32 + k]);
      pc += __shfl_xor(pc, 16);
      pc += __shfl_xor(pc, 8);
      pc += __shfl_xor(pc, 4);
      pc += __shfl_xor(pc, 2);
      pc += __shfl_xor(pc, 1);
      if (k == 0)
        out[(size_t)n * 6 + j] = __fadd_rn((float)(2048 - 2 * pc), g_bfc[j]);
    }
  }
}

// ------------------------------ launch --------------------------------------
extern "C" void kernel_launch(void* const* d_in, const int* in_sizes, int n_in,
                              void* d_out, int out_size, void* d_ws, size_t ws_size,
                              hipStream_t stream) {
  (void)d_ws; (void)ws_size; (void)n_in;
  Ptrs P;
  for (int i = 0; i < 27; ++i) P.p[i] = (const float*)d_in[i];

  hipLaunchKernelGGL(prepack_kernel, dim3(11), dim3(256), 0, stream, P);

  const float* x = (const float*)d_in[0];
  float* out = (float*)d_out;
  int B = in_sizes[0] / 768;                 // 4096
  hipLaunchKernelGGL(fused_kernel, dim3((B + 1) / 2), dim3(256), 0, stream, x, out, B);
}

// Round 12
// 74.863 us; speedup vs baseline: 1.4125x; 1.0138x over previous
//
#include <hip/hip_runtime.h>

typedef unsigned long long u64;
typedef unsigned int u32;

// ---------------- packed weights / integer thresholds (device globals) ------
// Layers 2/3/4: BN-decreasing ("flipped") channels are stored with
// COMPLEMENTED weight bits and threshold s -> 1-s (exactly equivalent).
// Only conv1 keeps a runtime flip mask (edge corrections are weight-dep).
__device__ u32 g_w1b[32];                 // 9 taps in low bits
__device__ u32 g_w2b[64 * 3];             // [c][k], bit = cin (0..31)
__device__ u64 g_w3b[128 * 3];            // [c][k], bit = cin (0..63)
__device__ u64 g_w4b[128 * 6 * 2];        // [c][h][hi], bit l = cin hi*64+l
__device__ u64 g_wfcb[6 * 32];            // [j][k]: w=k%16, hi=k/16, bit l -> i=(hi*64+l)*16+w
__device__ float g_bfc[6];

__device__ int g_s1[32], g_s2[64], g_s3[128], g_s4[128];   // integer S-thresholds
__device__ u64 g_flip1;                                     // conv1 flip mask

struct Ptrs { const float* p[27]; };

// exact f32 op order of the np reference: y = ((S + b) * inv) + t, no FMA
__device__ __forceinline__ int predS(int S, float b, float inv, float t) {
  float hv = __fadd_rn((float)S, b);
  float y = __fadd_rn(__fmul_rn(hv, inv), t);
  return y > 0.0f;
}

__device__ __forceinline__ void bn_fold(float b, float g, float be, float m, float v,
                                        float* ob, float* oinv, float* ot) {
  double iv = (double)g * (1.0 / sqrt((double)v + 1e-5));
  float invf = (float)iv;
  *ob = b;
  *oinv = invf;
  *ot = __fadd_rn(be, -__fmul_rn(m, invf));
}

// pred(S) == (S >= smin) XOR flip, exactly, for all integer S in range.
__device__ __forceinline__ void find_thr(float bias, float g, float be, float m, float v,
                                         int* smin, int* flip) {
  float b, inv, t;
  bn_fold(bias, g, be, m, v, &b, &inv, &t);
  int pl = predS(-2048, b, inv, t), ph = predS(2048, b, inv, t);
  if (pl && ph) { *smin = -4096; *flip = 0; }
  else if (!pl && !ph) { *smin = 4096; *flip = 0; }
  else if (!pl && ph) {
    int lo = -2048, hi = 2048;
    while (hi - lo > 1) { int md = (lo + hi) >> 1; if (predS(md, b, inv, t)) hi = md; else lo = md; }
    *smin = hi; *flip = 0;
  } else {
    int lo = -2048, hi = 2048;
    while (hi - lo > 1) { int md = (lo + hi) >> 1; if (predS(md, b, inv, t)) lo = md; else hi = md; }
    *smin = lo + 1; *flip = 1;
  }
}

// -------------------------- weight prepack ---------------------------------
__global__ __launch_bounds__(256) void prepack_kernel(Ptrs P) {
  int tid = threadIdx.x;
  int gid = blockIdx.x * 256 + tid;
  if (gid < 32) {                                   // conv1 thresholds (+flip mask)
    int c = gid, smin, flip;
    find_thr(P.p[2][c], P.p[3][c], P.p[4][c], P.p[5][c], P.p[6][c], &smin, &flip);
    g_s1[c] = smin;
    u64 fl = __ballot(flip != 0);
    if (c == 0) g_flip1 = (fl & 0xFFFFFFFFULL) | (fl << 32);
  } else if (gid >= 64 && gid < 128) {              // conv2 thresholds (flip folded)
    int c = gid - 64, smin, flip;
    find_thr(P.p[8][c], P.p[9][c], P.p[10][c], P.p[11][c], P.p[12][c], &smin, &flip);
    g_s2[c] = flip ? 1 - smin : smin;
  } else if (gid >= 128 && gid < 256) {             // conv3 thresholds
    int c = gid - 128, smin, flip;
    find_thr(P.p[14][c], P.p[15][c], P.p[16][c], P.p[17][c], P.p[18][c], &smin, &flip);
    g_s3[c] = flip ? 1 - smin : smin;
  } else if (gid >= 256 && gid < 384) {             // conv4 thresholds
    int c = gid - 256, smin, flip;
    find_thr(P.p[20][c], P.p[21][c], P.p[22][c], P.p[23][c], P.p[24][c], &smin, &flip);
    g_s4[c] = flip ? 1 - smin : smin;
  } else if (gid >= 384 && gid < 416) {             // w1 bits (flip NOT folded)
    int c = gid - 384;
    u32 b = 0;
    for (int k = 0; k < 9; ++k)
      if (P.p[1][c * 9 + k] > 0.0f) b |= (1u << k);
    g_w1b[c] = b;
  } else if (gid >= 416 && gid < 422) {
    g_bfc[gid - 416] = P.p[26][gid - 416];
  } else if (gid >= 512 && gid < 704) {             // w2 bits (complement if flip)
    int idx = gid - 512;
    int c = idx / 3, k = idx % 3;
    int smin, flip;
    find_thr(P.p[8][c], P.p[9][c], P.p[10][c], P.p[11][c], P.p[12][c], &smin, &flip);
    u32 b = 0;
    for (int cin = 0; cin < 32; ++cin)
      if (P.p[7][(c * 32 + cin) * 3 + k] > 0.0f) b |= (1u << cin);
    g_w2b[c * 3 + k] = flip ? ~b : b;
  } else if (gid >= 704 && gid < 1088) {            // w3 bits (complement if flip)
    int idx = gid - 704;
    int c = idx / 3, k = idx % 3;
    int smin, flip;
    find_thr(P.p[14][c], P.p[15][c], P.p[16][c], P.p[17][c], P.p[18][c], &smin, &flip);
    u64 b = 0;
    for (int cin = 0; cin < 64; ++cin)
      if (P.p[13][(c * 64 + cin) * 3 + k] > 0.0f) b |= (1ull << cin);
    g_w3b[c * 3 + k] = flip ? ~b : b;
  } else if (gid >= 1088 && gid < 2624) {           // w4 bits (complement if flip)
    int idx = gid - 1088;
    int c = idx / 12, r = idx % 12, h = r >> 1, hi = r & 1;
    int smin, flip;
    find_thr(P.p[20][c], P.p[21][c], P.p[22][c], P.p[23][c], P.p[24][c], &smin, &flip);
    u64 b = 0;
    for (int l = 0; l < 64; ++l) {
      int cin = hi * 64 + l;
      if (P.p[19][(c * 128 + cin) * 6 + h] > 0.0f) b |= (1ull << l);
    }
    g_w4b[(c * 6 + h) * 2 + hi] = flip ? ~b : b;
  } else if (gid >= 2624 && gid < 2816) {           // wfc bits (no BN)
    int idx = gid - 2624;
    int j = idx / 32, k = idx % 32;
    int w = k & 15, hi = k >> 4;
    u64 b = 0;
    for (int l = 0; l < 64; ++l) {
      int i = (hi * 64 + l) * 16 + w;
      if (P.p[25][j * 2048 + i] > 0.0f) b |= (1ull << l);
    }
    g_wfcb[j * 32 + k] = b;
  }
}

// ---------------- single-instruction primitives (inline asm) ----------------
__device__ __forceinline__ u64 ble(int P, int D) {   // ballot(P <= D)
  u64 m;
  asm("v_cmp_le_i32 %0, %1, %2" : "=s"(m) : "v"(P), "v"(D));
  return m;
}
__device__ __forceinline__ u64 bgt0f(float v) {      // ballot(v > 0.0f)
  u64 m;
  asm("v_cmp_lt_f32 %0, 0, %1" : "=s"(m) : "v"(v));
  return m;
}
__device__ __forceinline__ int bca(u32 x, int acc) { // acc + popc(x), one VALU
  int d;
  asm("v_bcnt_u32_b32 %0, %1, %2" : "=v"(d) : "v"(x), "v"(acc));
  return d;
}
// 11-bit field extract: (sval >> vshift) & 0x7FF, one VALU (VOP3, 1 SGPR)
__device__ __forceinline__ u32 bfe11(u32 sval, int vsh) {
  u32 d;
  asm("v_bfe_u32 %0, %1, %2, 11" : "=v"(d) : "s"(sval), "v"(vsh));
  return d;
}

// ----------------------- fused binary network ------------------------------
// ONE IMAGE PER 128-THREAD BLOCK (2 waves: rows 0-2 / 3-5). conv1->conv3 are
// row-local, fully in wave-uniform registers. p3s/c4s (cross-wave) in LDS.
// Barriers couple only the 2 waves of one image (no false inter-image dep).
struct WaveMem {
  alignas(16) u64 p3s[192];   // conv3+pool out (h*16+pw)*2+chanhalf
  u64 c4s[32];                // conv4 out w*2+chanhalf
};

__global__ __launch_bounds__(128, 16) void fused_kernel(const float* __restrict__ x,
                                                        float* __restrict__ out, int B) {
  const int tid = threadIdx.x;
  const int lane = tid & 63;
  const int half = tid >> 6;         // 0..1 : row-half of the image
  const int n = blockIdx.x;
  const bool active = (n < B);

  __shared__ WaveMem W;
  const float* xi = x + (size_t)n * 768;

  if (active) {
    // ---- per-lane constants for conv1..conv3 ----
    const int c1 = lane & 31;
    const bool isSub1 = (lane >= 32);
    const int vsh = isSub1 ? 4 : 0;    // per-lane window shift (VGPR)
    const u32 wv = g_w1b[c1];
    const u32 wv2 = wv << 2;
    const int s1v = g_s1[c1];
    const int D0i = (9 - s1v) >> 1;
    const int D0a = (5 - s1v + 2 * __popc(wv & 0x00F)) >> 1;
    const int D0b = (8 - s1v + 2 * __popc(wv & 0x100)) >> 1;
    const int D1a = (7 - s1v + 2 * __popc(wv & 0x003)) >> 1;
    const int D1b = (6 - s1v + 2 * __popc(wv & 0x1C0)) >> 1;
    const u64 fl1 = g_flip1;

    const u32 w0m = g_w2b[lane * 3 + 0];
    const u32 w1m = g_w2b[lane * 3 + 1];
    const u32 w2m = g_w2b[lane * 3 + 2];
    const int s2v = g_s2[lane];
    const int D96h = (96 - s2v) >> 1, D64h = (64 - s2v) >> 1;

    const u32* w3p = (const u32*)g_w3b;
    const u32 wl0l = w3p[(lane * 3 + 0) * 2], wl0h = w3p[(lane * 3 + 0) * 2 + 1];
    const u32 wl1l = w3p[(lane * 3 + 1) * 2], wl1h = w3p[(lane * 3 + 1) * 2 + 1];
    const u32 wl2l = w3p[(lane * 3 + 2) * 2], wl2h = w3p[(lane * 3 + 2) * 2 + 1];
    const u32 wh0l = w3p[((64 + lane) * 3 + 0) * 2], wh0h = w3p[((64 + lane) * 3 + 0) * 2 + 1];
    const u32 wh1l = w3p[((64 + lane) * 3 + 1) * 2], wh1h = w3p[((64 + lane) * 3 + 1) * 2 + 1];
    const u32 wh2l = w3p[((64 + lane) * 3 + 2) * 2], wh2h = w3p[((64 + lane) * 3 + 2) * 2 + 1];
    const int sa = g_s3[lane], sb = g_s3[64 + lane];
    const int Da192h = (192 - sa) >> 1, Da128h = (128 - sa) >> 1;
    const int Db192h = (192 - sb) >> 1, Db128h = (128 - sb) >> 1;

    // ---- process this wave's 3 rows ----
    #pragma unroll
    for (int hl = 0; hl < 3; ++hl) {
      const int h = half * 3 + hl;
      // stage A: binarize row into padded (<<4) form; all wave-uniform
      float v0 = xi[h * 128 + lane];
      float v1 = xi[h * 128 + 64 + lane];
      u64 m0 = bgt0f(v0);
      u64 m1 = bgt0f(v1);
      const u64 ra = m0 << 4;
      const u64 rb = (m0 >> 60) | (m1 << 4);
      const u64 rc = m1 >> 60;

      // conv1 + sign + pool: 16 ballots -> a64[j] covers pooled pos 2j,2j+1
      u64 a64[16];
      #pragma unroll
      for (int j = 0; j < 16; ++j) {
        u64 lo = (j < 8) ? ra : rb;
        u64 hi = (j < 8) ? rb : rc;
        const int sh = (8 * j) & 63;
        u64 Wq = (lo >> sh) | ((hi << 1) << (63 - sh));   // 15-bit superwindow
        u32 Wv = bfe11((u32)Wq, vsh);    // sub0: bits 0..10; sub1: bits 4..14
        int P0 = __popc((Wv ^ wv) & 0x1FF);
        int P1 = __popc((Wv ^ wv2) & 0x7FC);
        int D0 = D0i, D1 = D0i;
        if (j == 0)  { D0 = isSub1 ? D0i : D0a; D1 = isSub1 ? D0i : D1a; }
        if (j == 15) { D0 = isSub1 ? D0b : D0i; D1 = isSub1 ? D1b : D0i; }
        a64[j] = (ble(P0, D0) ^ fl1) | (ble(P1, D1) ^ fl1);
      }

      // u32 view of pooled row (static index -> SALU extract)
      auto AW = [&](int w) -> u32 {
        u64 v = a64[w >> 1];
        return (w & 1) ? (u32)(v >> 32) : (u32)v;
      };
      // conv2 (32->64, k=3, pad1) + sign: xor + bcnt-accumulate chains
      auto CONV2 = [&](int w, u32 am, u32 ac, u32 ap) -> u64 {
        int P, D;
        if (w == 0)       { P = bca(ap ^ w2m, __popc(ac ^ w1m)); D = D64h; }
        else if (w == 31) { P = bca(ac ^ w1m, __popc(am ^ w0m)); D = D64h; }
        else { P = bca(ap ^ w2m, bca(ac ^ w1m, __popc(am ^ w0m))); D = D96h; }
        return ble(P, D);
      };
      auto POP4 = [&](u32 a, u32 b, u32 c, u32 d) -> int {
        return bca(d, bca(c, bca(b, __popc(a))));
      };
      auto POP6 = [&](u32 a, u32 b, u32 c, u32 d, u32 e, u32 f) -> int {
        return bca(f, bca(e, bca(d, bca(c, bca(b, __popc(a))))));
      };
      // conv3 (64->128, k=3, pad1) + sign + pool; kind: 0=pw0, 1=mid, 2=pw15
      auto CONV3 = [&](int kind, u64 Au, u64 Bu, u64 Cu, u64 Du, int pt) {
        u32 Al = (u32)Au, Ah = (u32)(Au >> 32);
        u32 Bl = (u32)Bu, Bh = (u32)(Bu >> 32);
        u32 Cl = (u32)Cu, Ch = (u32)(Cu >> 32);
        u32 Dl = (u32)Du, Dh = (u32)(Du >> 32);
        int P0a, P1a, P0b, P1b, E0a, E1a, E0b, E1b;
        if (kind == 0) {       // out0 short (B,C taps1,2), out1 full (B,C,D)
          P0a = POP4(Bl^wl1l, Bh^wl1h, Cl^wl2l, Ch^wl2h);
          P1a = POP6(Bl^wl0l, Bh^wl0h, Cl^wl1l, Ch^wl1h, Dl^wl2l, Dh^wl2h);
          P0b = POP4(Bl^wh1l, Bh^wh1h, Cl^wh2l, Ch^wh2h);
          P1b = POP6(Bl^wh0l, Bh^wh0h, Cl^wh1l, Ch^wh1h, Dl^wh2l, Dh^wh2h);
          E0a = Da128h; E1a = Da192h; E0b = Db128h; E1b = Db192h;
        } else if (kind == 2) { // out0 full (A,B,C), out1 short (B,C taps0,1)
          P0a = POP6(Al^wl0l, Ah^wl0h, Bl^wl1l, Bh^wl1h, Cl^wl2l, Ch^wl2h);
          P1a = POP4(Bl^wl0l, Bh^wl0h, Cl^wl1l, Ch^wl1h);
          P0b = POP6(Al^wh0l, Ah^wh0h, Bl^wh1l, Bh^wh1h, Cl^wh2l, Ch^wh2h);
          P1b = POP4(Bl^wh0l, Bh^wh0h, Cl^wh1l, Ch^wh1h);
          E0a = Da192h; E1a = Da128h; E0b = Db192h; E1b = Db128h;
        } else {
          P0a = POP6(Al^wl0l, Ah^wl0h, Bl^wl1l, Bh^wl1h, Cl^wl2l, Ch^wl2h);
          P1a = POP6(Bl^wl0l, Bh^wl0h, Cl^wl1l, Ch^wl1h, Dl^wl2l, Dh^wl2h);
          P0b = POP6(Al^wh0l, Ah^wh0h, Bl^wh1l, Bh^wh1h, Cl^wh2l, Ch^wh2h);
          P1b = POP6(Bl^wh0l, Bh^wh0h, Cl^wh1l, Ch^wh1h, Dl^wh2l, Dh^wh2h);
          E0a = Da192h; E1a = Da192h; E0b = Db192h; E1b = Db192h;
        }
        u64 mm0 = ble(P0a, E0a) | ble(P1a, E1a);
        u64 mm1 = ble(P0b, E0b) | ble(P1b, E1b);
        if (lane == 0) {                  // one 16B-aligned b128 store
          ulonglong2 v2; v2.x = mm0; v2.y = mm1;
          *reinterpret_cast<ulonglong2*>(&W.p3s[2 * pt]) = v2;
        }
      };

      const int pt0 = h * 16;
      // software-pipelined conv2 -> conv3 over the row
      u64 cw0 = CONV2(0, AW(0), AW(0), AW(1));
      u64 cw1 = CONV2(1, AW(0), AW(1), AW(2));
      u64 cw2 = CONV2(2, AW(1), AW(2), AW(3));
      CONV3(0, cw0, cw0, cw1, cw2, pt0);           // pw=0: B=c2[0],C=c2[1],D=c2[2]
      u64 Ar = cw1, Br = cw2;                      // c2[2pw-1], c2[2pw] for pw=1
      #pragma unroll
      for (int pw = 1; pw <= 14; ++pw) {
        u64 Cr = CONV2(2 * pw + 1, AW(2 * pw), AW(2 * pw + 1), AW(2 * pw + 2));
        u64 Dr = CONV2(2 * pw + 2, AW(2 * pw + 1), AW(2 * pw + 2), AW(2 * pw + 3));
        CONV3(1, Ar, Br, Cr, Dr, pt0 + pw);
        Ar = Cr; Br = Dr;
      }
      u64 C15 = CONV2(31, AW(30), AW(31), AW(31));
      CONV3(2, Ar, Br, C15, C15, pt0 + 15);        // pw=15: A=c2[29],B=c2[30],C=c2[31]
    }
  }

  __syncthreads();   // conv4 mixes rows across the two waves

  if (active) {
    // ---- conv4 (128->128, k=(6,1)) + sign — split by output-channel half ----
    const u32* w4 = (const u32*)g_w4b;
    const int c = half * 64 + lane;
    u32 wt[24];
    #pragma unroll
    for (int h = 0; h < 6; ++h) {
      wt[h * 4 + 0] = w4[(c * 6 + h) * 4 + 0];
      wt[h * 4 + 1] = w4[(c * 6 + h) * 4 + 1];
      wt[h * 4 + 2] = w4[(c * 6 + h) * 4 + 2];
      wt[h * 4 + 3] = w4[(c * 6 + h) * 4 + 3];
    }
    const int Dch = (768 - g_s4[c]) >> 1;
    #pragma unroll 2
    for (int w = 0; w < 16; ++w) {
      const u32* p0 = (const u32*)&W.p3s[(0 * 16 + w) * 2];
      int acc = __popc(p0[0] ^ wt[0]);
      acc = bca(p0[1] ^ wt[1], acc);
      acc = bca(p0[2] ^ wt[2], acc);
      acc = bca(p0[3] ^ wt[3], acc);
      #pragma unroll
      for (int h = 1; h < 6; ++h) {
        const u32* p = (const u32*)&W.p3s[(h * 16 + w) * 2];
        acc = bca(p[0] ^ wt[h * 4 + 0], acc);
        acc = bca(p[1] ^ wt[h * 4 + 1], acc);
        acc = bca(p[2] ^ wt[h * 4 + 2], acc);
        acc = bca(p[3] ^ wt[h * 4 + 3], acc);
      }
      u64 m = ble(acc, Dch);
      if (lane == 0) W.c4s[2 * w + half] = m;
    }
  }

  __syncthreads();   // FC reads both channel halves

  if (active && half == 0) {
    // ---- FC: sign(h) . sign(wfc)^T + bfc  (shuffle reduce) ----
    const int k = lane & 31, hf = lane >> 5;
    u64 hw = W.c4s[(k & 15) * 2 + (k >> 4)];
    #pragma unroll
    for (int it = 0; it < 3; ++it) {
      int j = 2 * it + hf;
      int pc = __popcll(hw ^ g_wfcb[j * 32 + k]);
      pc += __shfl_xor(pc, 16);
      pc += __shfl_xor(pc, 8);
      pc += __shfl_xor(pc, 4);
      pc += __shfl_xor(pc, 2);
      pc += __shfl_xor(pc, 1);
      if (k == 0)
        out[(size_t)n * 6 + j] = __fadd_rn((float)(2048 - 2 * pc), g_bfc[j]);
    }
  }
}

// ------------------------------ launch --------------------------------------
extern "C" void kernel_launch(void* const* d_in, const int* in_sizes, int n_in,
                              void* d_out, int out_size, void* d_ws, size_t ws_size,
                              hipStream_t stream) {
  (void)d_ws; (void)ws_size; (void)n_in;
  Ptrs P;
  for (int i = 0; i < 27; ++i) P.p[i] = (const float*)d_in[i];

  hipLaunchKernelGGL(prepack_kernel, dim3(11), dim3(256), 0, stream, P);

  const float* x = (const float*)d_in[0];
  float* out = (float*)d_out;
  int B = in_sizes[0] / 768;                 // 4096
  hipLaunchKernelGGL(fused_kernel, dim3(B), dim3(128), 0, stream, x, out, B);
}